// Round 7
// baseline (1811.130 us; speedup 1.0000x reference)
//
#include <hip/hip_runtime.h>
#include <cstdint>
#include <cstddef>

#define N_NODES 100000
#define N_EDGES 1200000
#define ASIZE 256
#define HSIZE 64
#define NTYPES 4
#define NSTEPS 6
#define NGRAPH 64
#define PS 16   // pooling splits per graph

static __device__ __forceinline__ float sigmoidf_(float x) { return 1.0f / (1.0f + expf(-x)); }

// ---------------- CSR build (by dst) ----------------
__global__ void k_count(const int* __restrict__ dst, int* __restrict__ deg) {
    int e = blockIdx.x * 256 + threadIdx.x;
    if (e < N_EDGES) atomicAdd(&deg[dst[e]], 1);
}

__global__ void k_scan1(const int* __restrict__ deg, int* __restrict__ rs, int* __restrict__ part) {
    __shared__ int sh[256];
    int t = threadIdx.x;
    int base = blockIdx.x * 1024 + t * 4;
    int v0 = (base + 0 < N_NODES) ? deg[base + 0] : 0;
    int v1 = (base + 1 < N_NODES) ? deg[base + 1] : 0;
    int v2 = (base + 2 < N_NODES) ? deg[base + 2] : 0;
    int v3 = (base + 3 < N_NODES) ? deg[base + 3] : 0;
    int s = v0 + v1 + v2 + v3;
    sh[t] = s;
    __syncthreads();
    for (int off = 1; off < 256; off <<= 1) {
        int x = (t >= off) ? sh[t - off] : 0;
        __syncthreads();
        sh[t] += x;
        __syncthreads();
    }
    int excl = sh[t] - s;
    if (t == 255) part[blockIdx.x] = sh[255];
    if (base + 0 < N_NODES) rs[base + 0] = excl;
    if (base + 1 < N_NODES) rs[base + 1] = excl + v0;
    if (base + 2 < N_NODES) rs[base + 2] = excl + v0 + v1;
    if (base + 3 < N_NODES) rs[base + 3] = excl + v0 + v1 + v2;
}

__global__ void k_scan2(int* __restrict__ part, int* __restrict__ rs, int nb) {
    if (threadIdx.x == 0 && blockIdx.x == 0) {
        int run = 0;
        for (int i = 0; i < nb; ++i) { int v = part[i]; part[i] = run; run += v; }
        rs[N_NODES] = run;
    }
}

__global__ void k_scan3(int* __restrict__ rs, const int* __restrict__ part) {
    int i = blockIdx.x * 256 + threadIdx.x;
    if (i < N_NODES) rs[i] += part[i >> 10];
}

// colidx holds a precomputed float-offset into buf ([N][256] trans-only): src*256 + ety*64
__global__ void k_fill(const int* __restrict__ src, const int* __restrict__ dst,
                       const int* __restrict__ ety, const int* __restrict__ rs,
                       int* __restrict__ cur, int* __restrict__ colidx) {
    int e = blockIdx.x * 256 + threadIdx.x;
    if (e < N_EDGES) {
        int d = dst[e];
        int pos = rs[d] + atomicAdd(&cur[d], 1);
        colidx[pos] = src[e] * 256 + ety[e] * 64;
    }
}

// ---------------- weight prep ----------------
__global__ void k_prep2(const float* __restrict__ Wh, const float* __restrict__ Bh,
                        const float* __restrict__ eW, const float* __restrict__ eb,
                        const float* __restrict__ Wi, const float* __restrict__ Bi,
                        float* __restrict__ W256, float* __restrict__ b256,
                        float* __restrict__ Wh192, float* __restrict__ bh192,
                        float* __restrict__ WiA, float* __restrict__ biA) {
    int idx = blockIdx.x * 256 + threadIdx.x;
    if (idx < 64 * 256) {
        int k = idx / 256, c = idx % 256;
        W256[idx] = eW[(size_t)(c >> 6) * 4096 + k * 64 + (c & 63)];
    }
    if (idx < 64 * 192) {
        int k = idx / 192, m = idx % 192;
        int j = m / 3, g = m % 3;
        WiA[idx]   = Wi[(g * 64 + j) * 64 + k];
        Wh192[idx] = Wh[(g * 64 + j) * 64 + k];
    }
    if (idx < 256) b256[idx] = eb[idx];
    if (idx < 192) {
        biA[idx]   = Bi[(idx % 3) * 64 + idx / 3];
        bh192[idx] = Bh[(idx % 3) * 64 + idx / 3];
    }
}

// ---------------- generic tiled GEMM (used once: pre-loop trans of h0) ----------------
__global__ __launch_bounds__(256) void k_gemm(const float* __restrict__ X, int ldx, int K,
                                              const float* __restrict__ W, int ldw,
                                              const float* __restrict__ bias,
                                              float* __restrict__ Y, float* __restrict__ Y2,
                                              int M) {
    __shared__ float sX[128 * 66];
    __shared__ float sW[64 * 64];
    int tid = threadIdx.x;
    int mtile = blockIdx.x * 64;
    int ntile = blockIdx.y * 128;
    int tc4 = (tid & 15) * 4;
    int tr = tid >> 4;
    float4 acc[8];
#pragma unroll
    for (int i = 0; i < 8; ++i) acc[i] = make_float4(0.f, 0.f, 0.f, 0.f);

    int nkc = K >> 6;
    for (int kc = 0; kc < nkc; ++kc) {
        if (kc) __syncthreads();
#pragma unroll
        for (int i = 0; i < 8; ++i) {
            int lin4 = (i * 256 + tid) * 4;
            int nl = lin4 >> 6, kk = lin4 & 63;
            int n = ntile + nl;
            float4 v = make_float4(0.f, 0.f, 0.f, 0.f);
            if (n < N_NODES) v = *(const float4*)(X + (size_t)n * ldx + kc * 64 + kk);
            float* d = sX + nl * 66 + kk;
            d[0] = v.x; d[1] = v.y; d[2] = v.z; d[3] = v.w;
        }
#pragma unroll
        for (int i = 0; i < 4; ++i) {
            int lin4 = (i * 256 + tid) * 4;
            int kk = lin4 >> 6, c = lin4 & 63;
            float4 v = *(const float4*)(W + (size_t)(kc * 64 + kk) * ldw + mtile + c);
            *(float4*)(sW + kk * 64 + c) = v;
        }
        __syncthreads();
        const float* xr = sX + tr * 8 * 66;
        const float* wr = sW + tc4;
        for (int kk = 0; kk < 64; kk += 2) {
            float4 wA = *(const float4*)(wr + kk * 64);
            float4 wB = *(const float4*)(wr + (kk + 1) * 64);
            float xA[8], xB[8];
#pragma unroll
            for (int i = 0; i < 8; ++i) { xA[i] = xr[i * 66 + kk]; xB[i] = xr[i * 66 + kk + 1]; }
#pragma unroll
            for (int i = 0; i < 8; ++i) {
                acc[i].x = fmaf(xA[i], wA.x, acc[i].x);
                acc[i].y = fmaf(xA[i], wA.y, acc[i].y);
                acc[i].z = fmaf(xA[i], wA.z, acc[i].z);
                acc[i].w = fmaf(xA[i], wA.w, acc[i].w);
            }
#pragma unroll
            for (int i = 0; i < 8; ++i) {
                acc[i].x = fmaf(xB[i], wB.x, acc[i].x);
                acc[i].y = fmaf(xB[i], wB.y, acc[i].y);
                acc[i].z = fmaf(xB[i], wB.z, acc[i].z);
                acc[i].w = fmaf(xB[i], wB.w, acc[i].w);
            }
        }
    }
    float4 bv = *(const float4*)(bias + mtile + tc4);
#pragma unroll
    for (int i = 0; i < 8; ++i) {
        int n = ntile + tr * 8 + i;
        if (n < N_NODES) {
            float4 y;
            y.x = acc[i].x + bv.x; y.y = acc[i].y + bv.y;
            y.z = acc[i].z + bv.z; y.w = acc[i].w + bv.w;
            *(float4*)(Y + (size_t)n * M + mtile + tc4) = y;
            if (Y2) *(float4*)(Y2 + (size_t)n * M + mtile + tc4) = y;
        }
    }
}

// ---------------- reduce GEMM: h = h0 = ann[N][256] @ rW[256][64] + rb (K-pipelined) -------
__global__ __launch_bounds__(256) void k_gemm_red(const float* __restrict__ X,
                                                  const float* __restrict__ W,
                                                  const float* __restrict__ bias,
                                                  float* __restrict__ Y,
                                                  float* __restrict__ Y2) {
    __shared__ float sX[128 * 66];
    __shared__ float sW[64 * 64];
    int tid = threadIdx.x;
    int ntile = blockIdx.x * 128;
    int tc4 = (tid & 15) * 4;
    int tr = tid >> 4;
    int swr = tid >> 4;
    int swc = (tid & 15) * 4;

    float4 acc[8];
#pragma unroll
    for (int i = 0; i < 8; ++i) acc[i] = make_float4(0.f, 0.f, 0.f, 0.f);

    float4 xreg[8];
    float4 wreg[4];
#pragma unroll
    for (int i = 0; i < 8; ++i) {
        int lin4 = (i * 256 + tid) * 4;
        int nl = lin4 >> 6, kk = lin4 & 63;
        int n = ntile + nl;
        float4 v = make_float4(0.f, 0.f, 0.f, 0.f);
        if (n < N_NODES) v = *(const float4*)(X + (size_t)n * 256 + kk);
        xreg[i] = v;
    }
#pragma unroll
    for (int i = 0; i < 4; ++i)
        wreg[i] = *(const float4*)(W + (size_t)(i * 16 + swr) * 64 + swc);

    for (int kc = 0; kc < 4; ++kc) {
#pragma unroll
        for (int i = 0; i < 8; ++i) {
            int lin4 = (i * 256 + tid) * 4;
            int nl = lin4 >> 6, kk = lin4 & 63;
            float* d = sX + nl * 66 + kk;
            d[0] = xreg[i].x; d[1] = xreg[i].y; d[2] = xreg[i].z; d[3] = xreg[i].w;
        }
#pragma unroll
        for (int i = 0; i < 4; ++i)
            *(float4*)(sW + (i * 16 + swr) * 64 + swc) = wreg[i];
        __syncthreads();
        if (kc < 3) {
#pragma unroll
            for (int i = 0; i < 8; ++i) {
                int lin4 = (i * 256 + tid) * 4;
                int nl = lin4 >> 6, kk = lin4 & 63;
                int n = ntile + nl;
                float4 v = make_float4(0.f, 0.f, 0.f, 0.f);
                if (n < N_NODES) v = *(const float4*)(X + (size_t)n * 256 + (kc + 1) * 64 + kk);
                xreg[i] = v;
            }
#pragma unroll
            for (int i = 0; i < 4; ++i)
                wreg[i] = *(const float4*)(W + (size_t)((kc + 1) * 64 + i * 16 + swr) * 64 + swc);
        }
        const float* xr = sX + tr * 8 * 66;
        const float* wrp = sW + tc4;
        for (int kk = 0; kk < 64; kk += 2) {
            float4 wA = *(const float4*)(wrp + kk * 64);
            float4 wB = *(const float4*)(wrp + (kk + 1) * 64);
            float xA[8], xB[8];
#pragma unroll
            for (int i = 0; i < 8; ++i) { xA[i] = xr[i * 66 + kk]; xB[i] = xr[i * 66 + kk + 1]; }
#pragma unroll
            for (int i = 0; i < 8; ++i) {
                acc[i].x = fmaf(xA[i], wA.x, acc[i].x);
                acc[i].y = fmaf(xA[i], wA.y, acc[i].y);
                acc[i].z = fmaf(xA[i], wA.z, acc[i].z);
                acc[i].w = fmaf(xA[i], wA.w, acc[i].w);
            }
#pragma unroll
            for (int i = 0; i < 8; ++i) {
                acc[i].x = fmaf(xB[i], wB.x, acc[i].x);
                acc[i].y = fmaf(xB[i], wB.y, acc[i].y);
                acc[i].z = fmaf(xB[i], wB.z, acc[i].z);
                acc[i].w = fmaf(xB[i], wB.w, acc[i].w);
            }
        }
        if (kc < 3) __syncthreads();
    }
    float4 bv = *(const float4*)(bias + tc4);
#pragma unroll
    for (int i = 0; i < 8; ++i) {
        int n = ntile + tr * 8 + i;
        if (n < N_NODES) {
            float4 y;
            y.x = acc[i].x + bv.x; y.y = acc[i].y + bv.y;
            y.z = acc[i].z + bv.z; y.w = acc[i].w + bv.w;
            *(float4*)(Y + (size_t)n * 64 + tc4) = y;
            *(float4*)(Y2 + (size_t)n * 64 + tc4) = y;
        }
    }
}

// ---------------- fused: per-block aggregate + gi/gh GEMMs + GRU + trans ----------------
// Phase A: each wave aggregates 16 of the block's 64 nodes from bufIn (prev trans) via
// colidx gathers, writing results TRANSPOSED into sAT[k][node] — identical per-node
// accumulation procedure as the old standalone k_aggregate (masked batch, per-sub order,
// tail to sub0, shfl tree) -> bit-exact values. The VMEM-heavy gather of later blocks
// overlaps the VALU-heavy GEMM of earlier resident blocks (different pipes).
// Phases: gh (H @ Wh192, staged sXT) then gi (read sAT directly — no staging). Same
// kk-ascending fma chains per accumulator -> bit-exact. GRU epilogue, then trans tail
// writes bufOut (double-buffered vs bufIn to avoid the intra-launch race).
__global__ __launch_bounds__(256) void k_gruF5(const float* __restrict__ bufIn,
                                               const int* __restrict__ rs,
                                               const int* __restrict__ colidx,
                                               const float* __restrict__ WiA,
                                               const float* __restrict__ biA,
                                               const float* __restrict__ Wh192,
                                               const float* __restrict__ bh192,
                                               const float* __restrict__ W256,
                                               const float* __restrict__ b256,
                                               float* __restrict__ H,
                                               float* __restrict__ bufOut,
                                               int do_trans) {
    __shared__ float sAT[64 * 68];   // aggregate a, transposed [k][node]; reused as sHT
    __shared__ float sW[32 * 192];   // phase W chunks; reused as [64][64] trans W chunks
    __shared__ float sXT[32 * 68];   // H chunks transposed (gh phases)
    int tid = threadIdx.x;
    int ntile = blockIdx.x * 64;
    int lane = tid & 63;
    int wv = tid >> 6;               // wave 0..3
    int sub = lane >> 4;             // edge slot within group of 4
    int kq = (lane & 15) * 4;        // k quad

    // ---- phase A: aggregate (16 nodes per wave), results -> sAT transposed ----
    for (int j = 0; j < 16; ++j) {
        int nl = wv * 16 + j;
        int n = ntile + nl;
        if (n < N_NODES) {
            int beg = rs[n], end = rs[n + 1];           // wave-uniform
            int dg = end - beg;
            int c4end = beg + (dg & ~3);
            float4 a4 = make_float4(0.f, 0.f, 0.f, 0.f);
            int s = beg;
            for (; s + 31 < c4end; s += 32) {
                int c0 = colidx[s + sub];
                int c1 = colidx[s + 4 + sub];
                int c2 = colidx[s + 8 + sub];
                int c3 = colidx[s + 12 + sub];
                int c4 = colidx[s + 16 + sub];
                int c5 = colidx[s + 20 + sub];
                int c6 = colidx[s + 24 + sub];
                int c7 = colidx[s + 28 + sub];
                float4 v0 = *(const float4*)(bufIn + (size_t)c0 + kq);
                float4 v1 = *(const float4*)(bufIn + (size_t)c1 + kq);
                float4 v2 = *(const float4*)(bufIn + (size_t)c2 + kq);
                float4 v3 = *(const float4*)(bufIn + (size_t)c3 + kq);
                float4 v4 = *(const float4*)(bufIn + (size_t)c4 + kq);
                float4 v5 = *(const float4*)(bufIn + (size_t)c5 + kq);
                float4 v6 = *(const float4*)(bufIn + (size_t)c6 + kq);
                float4 v7 = *(const float4*)(bufIn + (size_t)c7 + kq);
                a4.x += v0.x; a4.y += v0.y; a4.z += v0.z; a4.w += v0.w;
                a4.x += v1.x; a4.y += v1.y; a4.z += v1.z; a4.w += v1.w;
                a4.x += v2.x; a4.y += v2.y; a4.z += v2.z; a4.w += v2.w;
                a4.x += v3.x; a4.y += v3.y; a4.z += v3.z; a4.w += v3.w;
                a4.x += v4.x; a4.y += v4.y; a4.z += v4.z; a4.w += v4.w;
                a4.x += v5.x; a4.y += v5.y; a4.z += v5.z; a4.w += v5.w;
                a4.x += v6.x; a4.y += v6.y; a4.z += v6.z; a4.w += v6.w;
                a4.x += v7.x; a4.y += v7.y; a4.z += v7.z; a4.w += v7.w;
            }
            {
                int nv = (c4end - s) >> 2;               // 0..7, wave-uniform
                float4 vv[7];
#pragma unroll
                for (int k = 0; k < 7; ++k) {
                    if (k < nv) {
                        int c = colidx[s + k * 4 + sub];
                        vv[k] = *(const float4*)(bufIn + (size_t)c + kq);
                    }
                }
#pragma unroll
                for (int k = 0; k < 7; ++k) {
                    if (k < nv) {
                        a4.x += vv[k].x; a4.y += vv[k].y; a4.z += vv[k].z; a4.w += vv[k].w;
                    }
                }
                s += nv * 4;
            }
            for (; s < end; ++s) {
                if (sub == 0) {
                    int c = colidx[s];
                    float4 v = *(const float4*)(bufIn + (size_t)c + kq);
                    a4.x += v.x; a4.y += v.y; a4.z += v.z; a4.w += v.w;
                }
            }
            float4 t4;
            t4.x = a4.x + __shfl_xor(a4.x, 16, 64);
            t4.y = a4.y + __shfl_xor(a4.y, 16, 64);
            t4.z = a4.z + __shfl_xor(a4.z, 16, 64);
            t4.w = a4.w + __shfl_xor(a4.w, 16, 64);
            float4 r4;
            r4.x = t4.x + __shfl_xor(t4.x, 32, 64);
            r4.y = t4.y + __shfl_xor(t4.y, 32, 64);
            r4.z = t4.z + __shfl_xor(t4.z, 32, 64);
            r4.w = t4.w + __shfl_xor(t4.w, 32, 64);
            if (sub == 0) {
                sAT[(kq + 0) * 68 + nl] = r4.x;
                sAT[(kq + 1) * 68 + nl] = r4.y;
                sAT[(kq + 2) * 68 + nl] = r4.z;
                sAT[(kq + 3) * 68 + nl] = r4.w;
            }
        }
    }

    // ---- GEMM phases: c=0,1 -> gh (acc[1]); c=2,3 -> gi (acc[0], from sAT) ----
    int tc = tid & 15;
    int tr = tid >> 4;
    float acc[2][4][12];
#pragma unroll
    for (int p = 0; p < 2; ++p)
#pragma unroll
        for (int i = 0; i < 4; ++i)
#pragma unroll
            for (int c = 0; c < 12; ++c) acc[p][i][c] = 0.f;

    int nl0 = tid >> 3;                 // staging: node 0..31
    int nl1 = (256 + tid) >> 3;         // node 32..63
    int kks = (tid & 7) * 4;            // k 0..28
    int nn0 = ntile + nl0, nn1 = ntile + nl1;
    int kkr = tid >> 3, wcc = (tid & 7) * 24;

    for (int c = 0; c < 4; ++c) {
        int isgh = (c < 2);
        int kc = c & 1;
        int ph = isgh ? 1 : 0;
        const float* Wsrc = isgh ? Wh192 : WiA;
        if (c) __syncthreads();          // prev chunk's LDS readers done
        if (isgh) {
            // stage H chunk transposed into sXT
            float4 v0 = make_float4(0.f, 0.f, 0.f, 0.f);
            float4 v1 = make_float4(0.f, 0.f, 0.f, 0.f);
            if (nn0 < N_NODES) v0 = *(const float4*)(H + (size_t)nn0 * 64 + kc * 32 + kks);
            if (nn1 < N_NODES) v1 = *(const float4*)(H + (size_t)nn1 * 64 + kc * 32 + kks);
            sXT[(kks + 0) * 68 + nl0] = v0.x;
            sXT[(kks + 1) * 68 + nl0] = v0.y;
            sXT[(kks + 2) * 68 + nl0] = v0.z;
            sXT[(kks + 3) * 68 + nl0] = v0.w;
            sXT[(kks + 0) * 68 + nl1] = v1.x;
            sXT[(kks + 1) * 68 + nl1] = v1.y;
            sXT[(kks + 2) * 68 + nl1] = v1.z;
            sXT[(kks + 3) * 68 + nl1] = v1.w;
        }
        {
            const float* srcp = Wsrc + (size_t)(kc * 32 + kkr) * 192 + wcc;
            float* d = sW + kkr * 192 + wcc;
#pragma unroll
            for (int u = 0; u < 6; ++u) *(float4*)(d + 4 * u) = *(const float4*)(srcp + 4 * u);
        }
        __syncthreads();
        const float* wr = sW + tc * 12;
        const float* xbase = isgh ? sXT : (sAT + (size_t)(kc * 32) * 68);
        for (int kk = 0; kk < 32; kk += 2) {
            float4 w0 = *(const float4*)(wr + kk * 192);
            float4 w1 = *(const float4*)(wr + kk * 192 + 4);
            float4 w2 = *(const float4*)(wr + kk * 192 + 8);
            float4 u0 = *(const float4*)(wr + (kk + 1) * 192);
            float4 u1 = *(const float4*)(wr + (kk + 1) * 192 + 4);
            float4 u2 = *(const float4*)(wr + (kk + 1) * 192 + 8);
            float4 xA4 = *(const float4*)(xbase + kk * 68 + tr * 4);
            float4 xB4 = *(const float4*)(xbase + (kk + 1) * 68 + tr * 4);
            float xA[4] = {xA4.x, xA4.y, xA4.z, xA4.w};
            float xB[4] = {xB4.x, xB4.y, xB4.z, xB4.w};
#pragma unroll
            for (int i = 0; i < 4; ++i) {
                acc[ph][i][0]  = fmaf(xA[i], w0.x, acc[ph][i][0]);
                acc[ph][i][1]  = fmaf(xA[i], w0.y, acc[ph][i][1]);
                acc[ph][i][2]  = fmaf(xA[i], w0.z, acc[ph][i][2]);
                acc[ph][i][3]  = fmaf(xA[i], w0.w, acc[ph][i][3]);
                acc[ph][i][4]  = fmaf(xA[i], w1.x, acc[ph][i][4]);
                acc[ph][i][5]  = fmaf(xA[i], w1.y, acc[ph][i][5]);
                acc[ph][i][6]  = fmaf(xA[i], w1.z, acc[ph][i][6]);
                acc[ph][i][7]  = fmaf(xA[i], w1.w, acc[ph][i][7]);
                acc[ph][i][8]  = fmaf(xA[i], w2.x, acc[ph][i][8]);
                acc[ph][i][9]  = fmaf(xA[i], w2.y, acc[ph][i][9]);
                acc[ph][i][10] = fmaf(xA[i], w2.z, acc[ph][i][10]);
                acc[ph][i][11] = fmaf(xA[i], w2.w, acc[ph][i][11]);
            }
#pragma unroll
            for (int i = 0; i < 4; ++i) {
                acc[ph][i][0]  = fmaf(xB[i], u0.x, acc[ph][i][0]);
                acc[ph][i][1]  = fmaf(xB[i], u0.y, acc[ph][i][1]);
                acc[ph][i][2]  = fmaf(xB[i], u0.z, acc[ph][i][2]);
                acc[ph][i][3]  = fmaf(xB[i], u0.w, acc[ph][i][3]);
                acc[ph][i][4]  = fmaf(xB[i], u1.x, acc[ph][i][4]);
                acc[ph][i][5]  = fmaf(xB[i], u1.y, acc[ph][i][5]);
                acc[ph][i][6]  = fmaf(xB[i], u1.z, acc[ph][i][6]);
                acc[ph][i][7]  = fmaf(xB[i], u1.w, acc[ph][i][7]);
                acc[ph][i][8]  = fmaf(xB[i], u2.x, acc[ph][i][8]);
                acc[ph][i][9]  = fmaf(xB[i], u2.y, acc[ph][i][9]);
                acc[ph][i][10] = fmaf(xB[i], u2.z, acc[ph][i][10]);
                acc[ph][i][11] = fmaf(xB[i], u2.w, acc[ph][i][11]);
            }
        }
    }
    __syncthreads();   // phase readers of sAT/sW done (sAT becomes sHT; sW reused by trans)

    // ---- epilogue: GRU gates; h_new -> global H and (transposed) sAT-as-sHT ----
    float bb[12], bh[12];
    {
        float4 b0 = *(const float4*)(biA + tc * 12);
        float4 b1 = *(const float4*)(biA + tc * 12 + 4);
        float4 b2 = *(const float4*)(biA + tc * 12 + 8);
        bb[0] = b0.x; bb[1] = b0.y; bb[2] = b0.z; bb[3] = b0.w;
        bb[4] = b1.x; bb[5] = b1.y; bb[6] = b1.z; bb[7] = b1.w;
        bb[8] = b2.x; bb[9] = b2.y; bb[10] = b2.z; bb[11] = b2.w;
        float4 c0 = *(const float4*)(bh192 + tc * 12);
        float4 c1 = *(const float4*)(bh192 + tc * 12 + 4);
        float4 c2 = *(const float4*)(bh192 + tc * 12 + 8);
        bh[0] = c0.x; bh[1] = c0.y; bh[2] = c0.z; bh[3] = c0.w;
        bh[4] = c1.x; bh[5] = c1.y; bh[6] = c1.z; bh[7] = c1.w;
        bh[8] = c2.x; bh[9] = c2.y; bh[10] = c2.z; bh[11] = c2.w;
    }
#pragma unroll
    for (int i = 0; i < 4; ++i) {
        int n = ntile + tr * 4 + i;
        if (n >= N_NODES) continue;
        float gg[12];
#pragma unroll
        for (int c = 0; c < 12; ++c) gg[c] = acc[1][i][c] + bh[c];
        float4 hv = *(const float4*)(H + (size_t)n * 64 + tc * 4);
        float res[4];
#pragma unroll
        for (int jj = 0; jj < 4; ++jj) {
            int c = jj * 3;
            float r = sigmoidf_(acc[0][i][c] + bb[c] + gg[c]);
            float z = sigmoidf_(acc[0][i][c + 1] + bb[c + 1] + gg[c + 1]);
            float nn = tanhf(acc[0][i][c + 2] + bb[c + 2] + r * gg[c + 2]);
            float hj = (jj == 0) ? hv.x : (jj == 1) ? hv.y : (jj == 2) ? hv.z : hv.w;
            res[jj] = (1.f - z) * nn + z * hj;
        }
        float4 o; o.x = res[0]; o.y = res[1]; o.z = res[2]; o.w = res[3];
        *(float4*)(H + (size_t)n * 64 + tc * 4) = o;
        if (do_trans) {
#pragma unroll
            for (int jj = 0; jj < 4; ++jj)
                sAT[(tc * 4 + jj) * 68 + (tr * 4 + i)] = res[jj];  // sHT
        }
    }
    // ---- trans tail: bufOut = h_new @ W256 + b256 (4 x 64-col chunks, W in sW region) ----
    if (do_trans) {
        __syncthreads();   // sHT writes visible to all
        int tc2 = tc * 4;
        for (int mt = 0; mt < 4; ++mt) {
            if (mt) __syncthreads();
#pragma unroll
            for (int i = 0; i < 4; ++i) {
                int idx = i * 256 + tid;            // 0..1023 float4s
                int row = idx >> 4, c4 = (idx & 15) * 4;
                *(float4*)(sW + row * 64 + c4) =
                    *(const float4*)(W256 + (size_t)row * 256 + mt * 64 + c4);
            }
            __syncthreads();
            float4 tacc[4];
#pragma unroll
            for (int i = 0; i < 4; ++i) tacc[i] = make_float4(0.f, 0.f, 0.f, 0.f);
            for (int kk = 0; kk < 64; kk += 2) {
                float4 wA = *(const float4*)(sW + kk * 64 + tc2);
                float4 wB = *(const float4*)(sW + (kk + 1) * 64 + tc2);
                float4 xA4 = *(const float4*)(sAT + kk * 68 + tr * 4);
                float4 xB4 = *(const float4*)(sAT + (kk + 1) * 68 + tr * 4);
                float xA[4] = {xA4.x, xA4.y, xA4.z, xA4.w};
                float xB[4] = {xB4.x, xB4.y, xB4.z, xB4.w};
#pragma unroll
                for (int i = 0; i < 4; ++i) {
                    tacc[i].x = fmaf(xA[i], wA.x, tacc[i].x);
                    tacc[i].y = fmaf(xA[i], wA.y, tacc[i].y);
                    tacc[i].z = fmaf(xA[i], wA.z, tacc[i].z);
                    tacc[i].w = fmaf(xA[i], wA.w, tacc[i].w);
                }
#pragma unroll
                for (int i = 0; i < 4; ++i) {
                    tacc[i].x = fmaf(xB[i], wB.x, tacc[i].x);
                    tacc[i].y = fmaf(xB[i], wB.y, tacc[i].y);
                    tacc[i].z = fmaf(xB[i], wB.z, tacc[i].z);
                    tacc[i].w = fmaf(xB[i], wB.w, tacc[i].w);
                }
            }
            float4 bv = *(const float4*)(b256 + mt * 64 + tc2);
#pragma unroll
            for (int i = 0; i < 4; ++i) {
                int n = ntile + tr * 4 + i;
                if (n < N_NODES) {
                    float4 y;
                    y.x = tacc[i].x + bv.x; y.y = tacc[i].y + bv.y;
                    y.z = tacc[i].z + bv.z; y.w = tacc[i].w + bv.w;
                    *(float4*)(bufOut + (size_t)n * 256 + mt * 64 + tc2) = y;
                }
            }
        }
    }
}

// ---------------- pooling: segmented, atomic-free, multi-block per graph ----------------
__global__ void k_bounds(const int* __restrict__ gid, int* __restrict__ start) {
    int n = blockIdx.x * 256 + threadIdx.x;
    if (n < N_NODES) {
        int g = gid[n];
        if (n == 0) {
            for (int x = 0; x <= g; ++x) start[x] = 0;
        } else {
            int pg = gid[n - 1];
            for (int x = pg + 1; x <= g; ++x) start[x] = n;
        }
        if (n == N_NODES - 1) {
            for (int x = g + 1; x <= NGRAPH; ++x) start[x] = N_NODES;
        }
    }
}

__global__ void k_gate2(const float* __restrict__ H, const float* __restrict__ H0,
                        const float* __restrict__ gW, const float* __restrict__ gb,
                        float* __restrict__ gate) {
    int l = threadIdx.x & 63;
    int n = blockIdx.x * 4 + (threadIdx.x >> 6);
    float v = H[(size_t)n * 64 + l] * gW[l] + H0[(size_t)n * 64 + l] * gW[64 + l];
    for (int off = 32; off > 0; off >>= 1) v += __shfl_xor(v, off, 64);
    if (l == 0) gate[n] = v + gb[0];
}

__global__ __launch_bounds__(64) void k_poolA(const float* __restrict__ gate,
                                              const int* __restrict__ start,
                                              float* __restrict__ pmax) {
    int g = blockIdx.x, s = blockIdx.y;
    int beg = start[g], len = start[g + 1] - beg;
    int sb = beg + (int)((long long)len * s / PS);
    int se = beg + (int)((long long)len * (s + 1) / PS);
    float m = -INFINITY;
    for (int n = sb + threadIdx.x; n < se; n += 64) m = fmaxf(m, gate[n]);
    for (int off = 32; off > 0; off >>= 1) m = fmaxf(m, __shfl_xor(m, off, 64));
    if (threadIdx.x == 0) pmax[g * PS + s] = m;
}

__global__ void k_poolB(const float* __restrict__ pmax, float* __restrict__ gm) {
    int g = threadIdx.x;  // 64 threads
    float m = -INFINITY;
    for (int s = 0; s < PS; ++s) m = fmaxf(m, pmax[g * PS + s]);
    if (!isfinite(m)) m = 0.0f;   // reference's empty-graph guard
    gm[g] = m;
}

__global__ __launch_bounds__(256) void k_poolC(const float* __restrict__ H,
                                               const float* __restrict__ H0,
                                               const float* __restrict__ gate,
                                               const int* __restrict__ start,
                                               const float* __restrict__ gm,
                                               float* __restrict__ pnum,
                                               float* __restrict__ pden) {
    int g = blockIdx.x, s = blockIdx.y;
    int beg = start[g], len = start[g + 1] - beg;
    int sb = beg + (int)((long long)len * s / PS);
    int se = beg + (int)((long long)len * (s + 1) / PS);
    int t = threadIdx.x;
    int lane = t & 63, wave = t >> 6;
    float m = gm[g];
    __shared__ float shh[4][64], sh0[4][64], ses[4];
    float ah = 0.f, ah0 = 0.f, es = 0.f;
    for (int n = sb + wave; n < se; n += 4) {
        float e = expf(gate[n] - m);
        es += e;
        ah  += e * H [(size_t)n * 64 + lane];
        ah0 += e * H0[(size_t)n * 64 + lane];
    }
    shh[wave][lane] = ah; sh0[wave][lane] = ah0;
    if (lane == 0) ses[wave] = es;
    __syncthreads();
    if (wave == 0) {
        float r  = shh[0][lane] + shh[1][lane] + shh[2][lane] + shh[3][lane];
        float r0 = sh0[0][lane] + sh0[1][lane] + sh0[2][lane] + sh0[3][lane];
        int base = (g * PS + s) * 128;
        pnum[base + lane]      = r;
        pnum[base + 64 + lane] = r0;
        if (lane == 0) pden[g * PS + s] = ses[0] + ses[1] + ses[2] + ses[3];
    }
}

__global__ __launch_bounds__(128) void k_poolD(const float* __restrict__ pnum,
                                               const float* __restrict__ pden,
                                               float* __restrict__ ro) {
    int g = blockIdx.x;
    int c = threadIdx.x;
    float den = 0.f;
    for (int s = 0; s < PS; ++s) den += pden[g * PS + s];
    float nu = 0.f;
    for (int s = 0; s < PS; ++s) nu += pnum[(g * PS + s) * 128 + c];
    ro[g * 128 + c] = (den > 0.f) ? nu / den : 0.f;
}

__global__ void k_logits(const float* __restrict__ ro, const float* __restrict__ oW,
                         const float* __restrict__ ob, float* __restrict__ out) {
    int t = threadIdx.x;
    int b = t >> 1;
    int c = t & 1;
    float acc = ob[c];
    for (int k = 0; k < 128; ++k) acc = fmaf(ro[b * 128 + k], oW[k * 2 + c], acc);
    out[b * 2 + c] = acc;
}

extern "C" void kernel_launch(void* const* d_in, const int* in_sizes, int n_in,
                              void* d_out, int out_size, void* d_ws, size_t ws_size,
                              hipStream_t stream) {
    (void)in_sizes; (void)n_in; (void)out_size; (void)ws_size;
    const float* ann = (const float*)d_in[0];
    const int* src   = (const int*)d_in[1];
    const int* dst   = (const int*)d_in[2];
    const int* ety   = (const int*)d_in[3];
    const int* gid   = (const int*)d_in[4];
    const float* rW  = (const float*)d_in[5];
    const float* rb  = (const float*)d_in[6];
    const float* eW  = (const float*)d_in[7];
    const float* eb  = (const float*)d_in[8];
    const float* Wi  = (const float*)d_in[9];
    const float* Bi  = (const float*)d_in[10];
    const float* Wh  = (const float*)d_in[11];
    const float* Bh  = (const float*)d_in[12];
    const float* gW  = (const float*)d_in[13];
    const float* gb  = (const float*)d_in[14];
    const float* oW  = (const float*)d_in[15];
    const float* ob  = (const float*)d_in[16];
    float* out = (float*)d_out;

    char* p = (char*)d_ws;
    auto take = [&](size_t nbytes) -> void* {
        void* r = (void*)p;
        p += (nbytes + 255) & ~((size_t)255);
        return r;
    };
    float* h0      = (float*)take((size_t)N_NODES * 64 * 4);
    float* h       = (float*)take((size_t)N_NODES * 64 * 4);
    float* buf1    = (float*)take((size_t)N_NODES * 256 * 4);   // trans ping
    float* buf2    = (float*)take((size_t)N_NODES * 256 * 4);   // trans pong
    float* W256    = (float*)take(64 * 256 * 4);
    float* b256    = (float*)take(256 * 4);
    float* Wh192   = (float*)take(64 * 192 * 4);
    float* bh192   = (float*)take(192 * 4);
    float* WiA     = (float*)take(64 * 192 * 4);
    float* biA     = (float*)take(192 * 4);
    int* deg       = (int*)take((size_t)N_NODES * 4);
    int* cur       = (int*)take((size_t)N_NODES * 4);
    int* rs        = (int*)take((size_t)(N_NODES + 1) * 4);
    int* part      = (int*)take(512);
    int* colidx    = (int*)take((size_t)N_EDGES * 4);
    float* gate    = (float*)take((size_t)N_NODES * 4);
    int* start     = (int*)take((size_t)(NGRAPH + 1) * 4);
    float* pmax    = (float*)take(NGRAPH * PS * 4);
    float* gm      = (float*)take(NGRAPH * 4);
    float* pnum    = (float*)take((size_t)NGRAPH * PS * 128 * 4);
    float* pden    = (float*)take(NGRAPH * PS * 4);
    float* ro      = (float*)take(NGRAPH * 128 * 4);

    // ---- CSR build (by dst)
    hipMemsetAsync(deg, 0, (size_t)N_NODES * 4, stream);
    hipMemsetAsync(cur, 0, (size_t)N_NODES * 4, stream);
    k_count<<<(N_EDGES + 255) / 256, 256, 0, stream>>>(dst, deg);
    int nb = (N_NODES + 1023) / 1024;  // 98
    k_scan1<<<nb, 256, 0, stream>>>(deg, rs, part);
    k_scan2<<<1, 64, 0, stream>>>(part, rs, nb);
    k_scan3<<<(N_NODES + 255) / 256, 256, 0, stream>>>(rs, part);
    k_fill<<<(N_EDGES + 255) / 256, 256, 0, stream>>>(src, dst, ety, rs, cur, colidx);

    // ---- weight prep + graph bounds
    k_prep2<<<112, 256, 0, stream>>>(Wh, Bh, eW, eb, Wi, Bi, W256, b256, Wh192, bh192, WiA, biA);
    k_bounds<<<(N_NODES + 255) / 256, 256, 0, stream>>>(gid, start);

    int ntiles = (N_NODES + 127) / 128;  // 782

    // ---- reduce layer: h = h0 = ann @ rW + rb (K-pipelined)
    k_gemm_red<<<ntiles, 256, 0, stream>>>(ann, rW, rb, h, h0);

    // ---- pre-loop trans of h0 into buf1
    k_gemm<<<dim3(4, ntiles), 256, 0, stream>>>(h, 64, 64, W256, 256, b256,
                                                buf1, nullptr, 256);

    // ---- message-passing steps: fused aggregate+GRU+trans, ping-pong trans buffers
    int nblk = (N_NODES + 63) / 64;   // 1563
    for (int s = 0; s < NSTEPS; ++s) {
        float* bin  = (s & 1) ? buf2 : buf1;
        float* bout = (s & 1) ? buf1 : buf2;
        k_gruF5<<<nblk, 256, 0, stream>>>(bin, rs, colidx, WiA, biA, Wh192, bh192,
                                          W256, b256, h, bout,
                                          (s < NSTEPS - 1) ? 1 : 0);
    }

    // ---- pooling + classifier (atomic-free, multi-block)
    k_gate2<<<N_NODES / 4, 256, 0, stream>>>(h, h0, gW, gb, gate);
    k_poolA<<<dim3(NGRAPH, PS), 64, 0, stream>>>(gate, start, pmax);
    k_poolB<<<1, 64, 0, stream>>>(pmax, gm);
    k_poolC<<<dim3(NGRAPH, PS), 256, 0, stream>>>(h, h0, gate, start, gm, pnum, pden);
    k_poolD<<<NGRAPH, 128, 0, stream>>>(pnum, pden, ro);
    k_logits<<<1, 128, 0, stream>>>(ro, oW, ob, out);
}

// Round 8
// 1575.556 us; speedup vs baseline: 1.1495x; 1.1495x over previous
//
#include <hip/hip_runtime.h>
#include <cstdint>
#include <cstddef>

#define N_NODES 100000
#define N_EDGES 1200000
#define ASIZE 256
#define HSIZE 64
#define NTYPES 4
#define NSTEPS 6
#define NGRAPH 64
#define PS 16   // pooling splits per graph

static __device__ __forceinline__ float sigmoidf_(float x) { return 1.0f / (1.0f + expf(-x)); }

// ---------------- CSR build (by dst) ----------------
__global__ void k_count(const int* __restrict__ dst, int* __restrict__ deg) {
    int e = blockIdx.x * 256 + threadIdx.x;
    if (e < N_EDGES) atomicAdd(&deg[dst[e]], 1);
}

__global__ void k_scan1(const int* __restrict__ deg, int* __restrict__ rs, int* __restrict__ part) {
    __shared__ int sh[256];
    int t = threadIdx.x;
    int base = blockIdx.x * 1024 + t * 4;
    int v0 = (base + 0 < N_NODES) ? deg[base + 0] : 0;
    int v1 = (base + 1 < N_NODES) ? deg[base + 1] : 0;
    int v2 = (base + 2 < N_NODES) ? deg[base + 2] : 0;
    int v3 = (base + 3 < N_NODES) ? deg[base + 3] : 0;
    int s = v0 + v1 + v2 + v3;
    sh[t] = s;
    __syncthreads();
    for (int off = 1; off < 256; off <<= 1) {
        int x = (t >= off) ? sh[t - off] : 0;
        __syncthreads();
        sh[t] += x;
        __syncthreads();
    }
    int excl = sh[t] - s;
    if (t == 255) part[blockIdx.x] = sh[255];
    if (base + 0 < N_NODES) rs[base + 0] = excl;
    if (base + 1 < N_NODES) rs[base + 1] = excl + v0;
    if (base + 2 < N_NODES) rs[base + 2] = excl + v0 + v1;
    if (base + 3 < N_NODES) rs[base + 3] = excl + v0 + v1 + v2;
}

__global__ void k_scan2(int* __restrict__ part, int* __restrict__ rs, int nb) {
    if (threadIdx.x == 0 && blockIdx.x == 0) {
        int run = 0;
        for (int i = 0; i < nb; ++i) { int v = part[i]; part[i] = run; run += v; }
        rs[N_NODES] = run;
    }
}

__global__ void k_scan3(int* __restrict__ rs, const int* __restrict__ part) {
    int i = blockIdx.x * 256 + threadIdx.x;
    if (i < N_NODES) rs[i] += part[i >> 10];
}

// colidx holds a precomputed float-offset into buf1 ([N][256] trans-only): src*256 + ety*64
__global__ void k_fill(const int* __restrict__ src, const int* __restrict__ dst,
                       const int* __restrict__ ety, const int* __restrict__ rs,
                       int* __restrict__ cur, int* __restrict__ colidx) {
    int e = blockIdx.x * 256 + threadIdx.x;
    if (e < N_EDGES) {
        int d = dst[e];
        int pos = rs[d] + atomicAdd(&cur[d], 1);
        colidx[pos] = src[e] * 256 + ety[e] * 64;
    }
}

// ---------------- weight prep ----------------
__global__ void k_prep2(const float* __restrict__ Wh, const float* __restrict__ Bh,
                        const float* __restrict__ eW, const float* __restrict__ eb,
                        const float* __restrict__ Wi, const float* __restrict__ Bi,
                        float* __restrict__ W256, float* __restrict__ b256,
                        float* __restrict__ Wh192, float* __restrict__ bh192,
                        float* __restrict__ WiA, float* __restrict__ biA) {
    int idx = blockIdx.x * 256 + threadIdx.x;
    if (idx < 64 * 256) {
        int k = idx / 256, c = idx % 256;
        W256[idx] = eW[(size_t)(c >> 6) * 4096 + k * 64 + (c & 63)];
    }
    if (idx < 64 * 192) {
        int k = idx / 192, m = idx % 192;
        int j = m / 3, g = m % 3;
        WiA[idx]   = Wi[(g * 64 + j) * 64 + k];
        Wh192[idx] = Wh[(g * 64 + j) * 64 + k];
    }
    if (idx < 256) b256[idx] = eb[idx];
    if (idx < 192) {
        biA[idx]   = Bi[(idx % 3) * 64 + idx / 3];
        bh192[idx] = Bh[(idx % 3) * 64 + idx / 3];
    }
}

// ---------------- generic tiled GEMM (used once: pre-loop trans of h0) ----------------
__global__ __launch_bounds__(256) void k_gemm(const float* __restrict__ X, int ldx, int K,
                                              const float* __restrict__ W, int ldw,
                                              const float* __restrict__ bias,
                                              float* __restrict__ Y, float* __restrict__ Y2,
                                              int M) {
    __shared__ float sX[128 * 66];
    __shared__ float sW[64 * 64];
    int tid = threadIdx.x;
    int mtile = blockIdx.x * 64;
    int ntile = blockIdx.y * 128;
    int tc4 = (tid & 15) * 4;
    int tr = tid >> 4;
    float4 acc[8];
#pragma unroll
    for (int i = 0; i < 8; ++i) acc[i] = make_float4(0.f, 0.f, 0.f, 0.f);

    int nkc = K >> 6;
    for (int kc = 0; kc < nkc; ++kc) {
        if (kc) __syncthreads();
#pragma unroll
        for (int i = 0; i < 8; ++i) {
            int lin4 = (i * 256 + tid) * 4;
            int nl = lin4 >> 6, kk = lin4 & 63;
            int n = ntile + nl;
            float4 v = make_float4(0.f, 0.f, 0.f, 0.f);
            if (n < N_NODES) v = *(const float4*)(X + (size_t)n * ldx + kc * 64 + kk);
            float* d = sX + nl * 66 + kk;
            d[0] = v.x; d[1] = v.y; d[2] = v.z; d[3] = v.w;
        }
#pragma unroll
        for (int i = 0; i < 4; ++i) {
            int lin4 = (i * 256 + tid) * 4;
            int kk = lin4 >> 6, c = lin4 & 63;
            float4 v = *(const float4*)(W + (size_t)(kc * 64 + kk) * ldw + mtile + c);
            *(float4*)(sW + kk * 64 + c) = v;
        }
        __syncthreads();
        const float* xr = sX + tr * 8 * 66;
        const float* wr = sW + tc4;
        for (int kk = 0; kk < 64; kk += 2) {
            float4 wA = *(const float4*)(wr + kk * 64);
            float4 wB = *(const float4*)(wr + (kk + 1) * 64);
            float xA[8], xB[8];
#pragma unroll
            for (int i = 0; i < 8; ++i) { xA[i] = xr[i * 66 + kk]; xB[i] = xr[i * 66 + kk + 1]; }
#pragma unroll
            for (int i = 0; i < 8; ++i) {
                acc[i].x = fmaf(xA[i], wA.x, acc[i].x);
                acc[i].y = fmaf(xA[i], wA.y, acc[i].y);
                acc[i].z = fmaf(xA[i], wA.z, acc[i].z);
                acc[i].w = fmaf(xA[i], wA.w, acc[i].w);
            }
#pragma unroll
            for (int i = 0; i < 8; ++i) {
                acc[i].x = fmaf(xB[i], wB.x, acc[i].x);
                acc[i].y = fmaf(xB[i], wB.y, acc[i].y);
                acc[i].z = fmaf(xB[i], wB.z, acc[i].z);
                acc[i].w = fmaf(xB[i], wB.w, acc[i].w);
            }
        }
    }
    float4 bv = *(const float4*)(bias + mtile + tc4);
#pragma unroll
    for (int i = 0; i < 8; ++i) {
        int n = ntile + tr * 8 + i;
        if (n < N_NODES) {
            float4 y;
            y.x = acc[i].x + bv.x; y.y = acc[i].y + bv.y;
            y.z = acc[i].z + bv.z; y.w = acc[i].w + bv.w;
            *(float4*)(Y + (size_t)n * M + mtile + tc4) = y;
            if (Y2) *(float4*)(Y2 + (size_t)n * M + mtile + tc4) = y;
        }
    }
}

// ---------------- reduce GEMM: h = h0 = ann[N][256] @ rW[256][64] + rb (K-pipelined) -------
__global__ __launch_bounds__(256) void k_gemm_red(const float* __restrict__ X,
                                                  const float* __restrict__ W,
                                                  const float* __restrict__ bias,
                                                  float* __restrict__ Y,
                                                  float* __restrict__ Y2) {
    __shared__ float sX[128 * 66];
    __shared__ float sW[64 * 64];
    int tid = threadIdx.x;
    int ntile = blockIdx.x * 128;
    int tc4 = (tid & 15) * 4;
    int tr = tid >> 4;
    int swr = tid >> 4;
    int swc = (tid & 15) * 4;

    float4 acc[8];
#pragma unroll
    for (int i = 0; i < 8; ++i) acc[i] = make_float4(0.f, 0.f, 0.f, 0.f);

    float4 xreg[8];
    float4 wreg[4];
#pragma unroll
    for (int i = 0; i < 8; ++i) {
        int lin4 = (i * 256 + tid) * 4;
        int nl = lin4 >> 6, kk = lin4 & 63;
        int n = ntile + nl;
        float4 v = make_float4(0.f, 0.f, 0.f, 0.f);
        if (n < N_NODES) v = *(const float4*)(X + (size_t)n * 256 + kk);
        xreg[i] = v;
    }
#pragma unroll
    for (int i = 0; i < 4; ++i)
        wreg[i] = *(const float4*)(W + (size_t)(i * 16 + swr) * 64 + swc);

    for (int kc = 0; kc < 4; ++kc) {
#pragma unroll
        for (int i = 0; i < 8; ++i) {
            int lin4 = (i * 256 + tid) * 4;
            int nl = lin4 >> 6, kk = lin4 & 63;
            float* d = sX + nl * 66 + kk;
            d[0] = xreg[i].x; d[1] = xreg[i].y; d[2] = xreg[i].z; d[3] = xreg[i].w;
        }
#pragma unroll
        for (int i = 0; i < 4; ++i)
            *(float4*)(sW + (i * 16 + swr) * 64 + swc) = wreg[i];
        __syncthreads();
        if (kc < 3) {
#pragma unroll
            for (int i = 0; i < 8; ++i) {
                int lin4 = (i * 256 + tid) * 4;
                int nl = lin4 >> 6, kk = lin4 & 63;
                int n = ntile + nl;
                float4 v = make_float4(0.f, 0.f, 0.f, 0.f);
                if (n < N_NODES) v = *(const float4*)(X + (size_t)n * 256 + (kc + 1) * 64 + kk);
                xreg[i] = v;
            }
#pragma unroll
            for (int i = 0; i < 4; ++i)
                wreg[i] = *(const float4*)(W + (size_t)((kc + 1) * 64 + i * 16 + swr) * 64 + swc);
        }
        const float* xr = sX + tr * 8 * 66;
        const float* wrp = sW + tc4;
        for (int kk = 0; kk < 64; kk += 2) {
            float4 wA = *(const float4*)(wrp + kk * 64);
            float4 wB = *(const float4*)(wrp + (kk + 1) * 64);
            float xA[8], xB[8];
#pragma unroll
            for (int i = 0; i < 8; ++i) { xA[i] = xr[i * 66 + kk]; xB[i] = xr[i * 66 + kk + 1]; }
#pragma unroll
            for (int i = 0; i < 8; ++i) {
                acc[i].x = fmaf(xA[i], wA.x, acc[i].x);
                acc[i].y = fmaf(xA[i], wA.y, acc[i].y);
                acc[i].z = fmaf(xA[i], wA.z, acc[i].z);
                acc[i].w = fmaf(xA[i], wA.w, acc[i].w);
            }
#pragma unroll
            for (int i = 0; i < 8; ++i) {
                acc[i].x = fmaf(xB[i], wB.x, acc[i].x);
                acc[i].y = fmaf(xB[i], wB.y, acc[i].y);
                acc[i].z = fmaf(xB[i], wB.z, acc[i].z);
                acc[i].w = fmaf(xB[i], wB.w, acc[i].w);
            }
        }
        if (kc < 3) __syncthreads();
    }
    float4 bv = *(const float4*)(bias + tc4);
#pragma unroll
    for (int i = 0; i < 8; ++i) {
        int n = ntile + tr * 8 + i;
        if (n < N_NODES) {
            float4 y;
            y.x = acc[i].x + bv.x; y.y = acc[i].y + bv.y;
            y.z = acc[i].z + bv.z; y.w = acc[i].w + bv.w;
            *(float4*)(Y + (size_t)n * 64 + tc4) = y;
            *(float4*)(Y2 + (size_t)n * 64 + tc4) = y;
        }
    }
}

// ---------------- edge aggregate: a[n] = sum of incoming trans rows from buf1 ----------------
// 2 nodes per wave, loads interleaved: rs/colidx/gather loads for BOTH nodes (plus their
// <4-edge tails) are issued before either node accumulates -> latency epochs amortized 2x
// and the tail epoch is fused. Per-node fp accumulation order is IDENTICAL to the previous
// version (batch k ascending per sub; tail appended to sub0 after its batch adds; shfl-tree
// (a0+a1)+(a2+a3)) -> bit-exact.
__global__ void k_aggregate(const float* __restrict__ buf1, const int* __restrict__ rs,
                            const int* __restrict__ colidx, float* __restrict__ a) {
    int lane = threadIdx.x & 63;
    int wv = threadIdx.x >> 6;
    int n0 = blockIdx.x * 8 + wv * 2;   // 12500 blocks * 8 = N exactly
    int n1 = n0 + 1;
    int sub = lane >> 4;            // edge slot within group of 4
    int kq = (lane & 15) * 4;       // k quad handled by this lane
    int beg0 = rs[n0];
    int mid  = rs[n0 + 1];
    int end1 = rs[n1 + 1];
    int end0 = mid, beg1 = mid;     // wave-uniform
    float4 acc0 = make_float4(0.f, 0.f, 0.f, 0.f);
    float4 acc1 = make_float4(0.f, 0.f, 0.f, 0.f);
    int s0 = beg0, s1 = beg1;
    int c4e0 = beg0 + ((end0 - beg0) & ~3);
    int c4e1 = beg1 + ((end1 - beg1) & ~3);
    // rare big-degree path (deg>=32), sequential per node, same order as before
    for (; s0 + 31 < c4e0; s0 += 32) {
        int c0 = colidx[s0 + sub],      c1 = colidx[s0 + 4 + sub];
        int c2 = colidx[s0 + 8 + sub],  c3 = colidx[s0 + 12 + sub];
        int c4 = colidx[s0 + 16 + sub], c5 = colidx[s0 + 20 + sub];
        int c6 = colidx[s0 + 24 + sub], c7 = colidx[s0 + 28 + sub];
        float4 v0 = *(const float4*)(buf1 + (size_t)c0 + kq);
        float4 v1 = *(const float4*)(buf1 + (size_t)c1 + kq);
        float4 v2 = *(const float4*)(buf1 + (size_t)c2 + kq);
        float4 v3 = *(const float4*)(buf1 + (size_t)c3 + kq);
        float4 v4 = *(const float4*)(buf1 + (size_t)c4 + kq);
        float4 v5 = *(const float4*)(buf1 + (size_t)c5 + kq);
        float4 v6 = *(const float4*)(buf1 + (size_t)c6 + kq);
        float4 v7 = *(const float4*)(buf1 + (size_t)c7 + kq);
        acc0.x += v0.x; acc0.y += v0.y; acc0.z += v0.z; acc0.w += v0.w;
        acc0.x += v1.x; acc0.y += v1.y; acc0.z += v1.z; acc0.w += v1.w;
        acc0.x += v2.x; acc0.y += v2.y; acc0.z += v2.z; acc0.w += v2.w;
        acc0.x += v3.x; acc0.y += v3.y; acc0.z += v3.z; acc0.w += v3.w;
        acc0.x += v4.x; acc0.y += v4.y; acc0.z += v4.z; acc0.w += v4.w;
        acc0.x += v5.x; acc0.y += v5.y; acc0.z += v5.z; acc0.w += v5.w;
        acc0.x += v6.x; acc0.y += v6.y; acc0.z += v6.z; acc0.w += v6.w;
        acc0.x += v7.x; acc0.y += v7.y; acc0.z += v7.z; acc0.w += v7.w;
    }
    for (; s1 + 31 < c4e1; s1 += 32) {
        int c0 = colidx[s1 + sub],      c1 = colidx[s1 + 4 + sub];
        int c2 = colidx[s1 + 8 + sub],  c3 = colidx[s1 + 12 + sub];
        int c4 = colidx[s1 + 16 + sub], c5 = colidx[s1 + 20 + sub];
        int c6 = colidx[s1 + 24 + sub], c7 = colidx[s1 + 28 + sub];
        float4 v0 = *(const float4*)(buf1 + (size_t)c0 + kq);
        float4 v1 = *(const float4*)(buf1 + (size_t)c1 + kq);
        float4 v2 = *(const float4*)(buf1 + (size_t)c2 + kq);
        float4 v3 = *(const float4*)(buf1 + (size_t)c3 + kq);
        float4 v4 = *(const float4*)(buf1 + (size_t)c4 + kq);
        float4 v5 = *(const float4*)(buf1 + (size_t)c5 + kq);
        float4 v6 = *(const float4*)(buf1 + (size_t)c6 + kq);
        float4 v7 = *(const float4*)(buf1 + (size_t)c7 + kq);
        acc1.x += v0.x; acc1.y += v0.y; acc1.z += v0.z; acc1.w += v0.w;
        acc1.x += v1.x; acc1.y += v1.y; acc1.z += v1.z; acc1.w += v1.w;
        acc1.x += v2.x; acc1.y += v2.y; acc1.z += v2.z; acc1.w += v2.w;
        acc1.x += v3.x; acc1.y += v3.y; acc1.z += v3.z; acc1.w += v3.w;
        acc1.x += v4.x; acc1.y += v4.y; acc1.z += v4.z; acc1.w += v4.w;
        acc1.x += v5.x; acc1.y += v5.y; acc1.z += v5.z; acc1.w += v5.w;
        acc1.x += v6.x; acc1.y += v6.y; acc1.z += v6.z; acc1.w += v6.w;
        acc1.x += v7.x; acc1.y += v7.y; acc1.z += v7.z; acc1.w += v7.w;
    }
    // fused final epoch: masked batches + tails for BOTH nodes, all loads in flight together
    {
        int nv0 = (c4e0 - s0) >> 2;           // 0..7, wave-uniform
        int nv1 = (c4e1 - s1) >> 2;
        int tb0 = s0 + nv0 * 4, tn0 = end0 - tb0;   // tail base/count 0..3, wave-uniform
        int tb1 = s1 + nv1 * 4, tn1 = end1 - tb1;
        float4 vv0[7], vv1[7], tv0[3], tv1[3];
#pragma unroll
        for (int k = 0; k < 7; ++k) {
            if (k < nv0) {
                int c = colidx[s0 + k * 4 + sub];
                vv0[k] = *(const float4*)(buf1 + (size_t)c + kq);
            }
        }
#pragma unroll
        for (int k = 0; k < 7; ++k) {
            if (k < nv1) {
                int c = colidx[s1 + k * 4 + sub];
                vv1[k] = *(const float4*)(buf1 + (size_t)c + kq);
            }
        }
#pragma unroll
        for (int k = 0; k < 3; ++k) {
            if (k < tn0) {
                int c = colidx[tb0 + k];        // wave-uniform address; value used on sub0
                tv0[k] = *(const float4*)(buf1 + (size_t)c + kq);
            }
        }
#pragma unroll
        for (int k = 0; k < 3; ++k) {
            if (k < tn1) {
                int c = colidx[tb1 + k];
                tv1[k] = *(const float4*)(buf1 + (size_t)c + kq);
            }
        }
        // node0: batch adds (k ascending), then tail appended to sub0 (same old order)
#pragma unroll
        for (int k = 0; k < 7; ++k) {
            if (k < nv0) {
                acc0.x += vv0[k].x; acc0.y += vv0[k].y; acc0.z += vv0[k].z; acc0.w += vv0[k].w;
            }
        }
        if (sub == 0) {
#pragma unroll
            for (int k = 0; k < 3; ++k) {
                if (k < tn0) {
                    acc0.x += tv0[k].x; acc0.y += tv0[k].y; acc0.z += tv0[k].z; acc0.w += tv0[k].w;
                }
            }
        }
        float4 t4, r4;
        t4.x = acc0.x + __shfl_xor(acc0.x, 16, 64);
        t4.y = acc0.y + __shfl_xor(acc0.y, 16, 64);
        t4.z = acc0.z + __shfl_xor(acc0.z, 16, 64);
        t4.w = acc0.w + __shfl_xor(acc0.w, 16, 64);
        r4.x = t4.x + __shfl_xor(t4.x, 32, 64);
        r4.y = t4.y + __shfl_xor(t4.y, 32, 64);
        r4.z = t4.z + __shfl_xor(t4.z, 32, 64);
        r4.w = t4.w + __shfl_xor(t4.w, 32, 64);
        if (sub == 0) *(float4*)(a + (size_t)n0 * 64 + kq) = r4;
        // node1
#pragma unroll
        for (int k = 0; k < 7; ++k) {
            if (k < nv1) {
                acc1.x += vv1[k].x; acc1.y += vv1[k].y; acc1.z += vv1[k].z; acc1.w += vv1[k].w;
            }
        }
        if (sub == 0) {
#pragma unroll
            for (int k = 0; k < 3; ++k) {
                if (k < tn1) {
                    acc1.x += tv1[k].x; acc1.y += tv1[k].y; acc1.z += tv1[k].z; acc1.w += tv1[k].w;
                }
            }
        }
        t4.x = acc1.x + __shfl_xor(acc1.x, 16, 64);
        t4.y = acc1.y + __shfl_xor(acc1.y, 16, 64);
        t4.z = acc1.z + __shfl_xor(acc1.z, 16, 64);
        t4.w = acc1.w + __shfl_xor(acc1.w, 16, 64);
        r4.x = t4.x + __shfl_xor(t4.x, 32, 64);
        r4.y = t4.y + __shfl_xor(t4.y, 32, 64);
        r4.z = t4.z + __shfl_xor(t4.z, 32, 64);
        r4.w = t4.w + __shfl_xor(t4.w, 32, 64);
        if (sub == 0) *(float4*)(a + (size_t)n1 * 64 + kq) = r4;
    }
}

// ---------------- fused: gi-GEMM + gh-GEMM + GRU + trans-GEMM for next step ----------------
// (exact R4 k_gruF3 — proven 143us: sW staged in LDS, transposed-X b128 reads)
__global__ __launch_bounds__(256) void k_gruF3(const float* __restrict__ A,
                                               const float* __restrict__ WiA,
                                               const float* __restrict__ biA,
                                               const float* __restrict__ Wh192,
                                               const float* __restrict__ bh192,
                                               const float* __restrict__ W256,
                                               const float* __restrict__ b256,
                                               float* __restrict__ H,
                                               float* __restrict__ buf1,
                                               int do_trans) {
    __shared__ float sXT[32 * 68];   // [k][node], stride 68 (16B-aligned rows)
    __shared__ float sW[32 * 192];   // gi/gh W chunks; reused as [64][64] for trans chunks
    __shared__ float sHT[64 * 68];   // h_new transposed [k][node]
    int tid = threadIdx.x;
    int ntile = blockIdx.x * 64;
    int tc = tid & 15;
    int tr = tid >> 4;
    float acc[2][4][12];
#pragma unroll
    for (int p = 0; p < 2; ++p)
#pragma unroll
        for (int i = 0; i < 4; ++i)
#pragma unroll
            for (int c = 0; c < 12; ++c) acc[p][i][c] = 0.f;

#pragma unroll
    for (int ph = 0; ph < 2; ++ph) {
        const float* Xsrc = (ph == 0) ? A : H;
        const float* Wsrc = (ph == 0) ? WiA : Wh192;
        for (int kc = 0; kc < 2; ++kc) {
            if (ph || kc) __syncthreads();
            // stage X transposed: 64 nodes x 32 k
#pragma unroll
            for (int i = 0; i < 2; ++i) {
                int lin = i * 256 + tid;             // 0..511 float4s
                int nl = lin >> 3;                   // node 0..63
                int kk = (lin & 7) * 4;              // k 0..28
                int n = ntile + nl;
                float4 v = make_float4(0.f, 0.f, 0.f, 0.f);
                if (n < N_NODES) v = *(const float4*)(Xsrc + (size_t)n * 64 + kc * 32 + kk);
                sXT[(kk + 0) * 68 + nl] = v.x;
                sXT[(kk + 1) * 68 + nl] = v.y;
                sXT[(kk + 2) * 68 + nl] = v.z;
                sXT[(kk + 3) * 68 + nl] = v.w;
            }
            {
                int kk = tid >> 3, c = (tid & 7) * 24;
                const float* srcp = Wsrc + (size_t)(kc * 32 + kk) * 192 + c;
                float* d = sW + kk * 192 + c;
#pragma unroll
                for (int u = 0; u < 6; ++u) *(float4*)(d + 4 * u) = *(const float4*)(srcp + 4 * u);
            }
            __syncthreads();
            const float* wr = sW + tc * 12;
            for (int kk = 0; kk < 32; kk += 2) {
                float4 w0 = *(const float4*)(wr + kk * 192);
                float4 w1 = *(const float4*)(wr + kk * 192 + 4);
                float4 w2 = *(const float4*)(wr + kk * 192 + 8);
                float4 u0 = *(const float4*)(wr + (kk + 1) * 192);
                float4 u1 = *(const float4*)(wr + (kk + 1) * 192 + 4);
                float4 u2 = *(const float4*)(wr + (kk + 1) * 192 + 8);
                float4 xA4 = *(const float4*)(sXT + kk * 68 + tr * 4);
                float4 xB4 = *(const float4*)(sXT + (kk + 1) * 68 + tr * 4);
                float xA[4] = {xA4.x, xA4.y, xA4.z, xA4.w};
                float xB[4] = {xB4.x, xB4.y, xB4.z, xB4.w};
#pragma unroll
                for (int i = 0; i < 4; ++i) {
                    acc[ph][i][0]  = fmaf(xA[i], w0.x, acc[ph][i][0]);
                    acc[ph][i][1]  = fmaf(xA[i], w0.y, acc[ph][i][1]);
                    acc[ph][i][2]  = fmaf(xA[i], w0.z, acc[ph][i][2]);
                    acc[ph][i][3]  = fmaf(xA[i], w0.w, acc[ph][i][3]);
                    acc[ph][i][4]  = fmaf(xA[i], w1.x, acc[ph][i][4]);
                    acc[ph][i][5]  = fmaf(xA[i], w1.y, acc[ph][i][5]);
                    acc[ph][i][6]  = fmaf(xA[i], w1.z, acc[ph][i][6]);
                    acc[ph][i][7]  = fmaf(xA[i], w1.w, acc[ph][i][7]);
                    acc[ph][i][8]  = fmaf(xA[i], w2.x, acc[ph][i][8]);
                    acc[ph][i][9]  = fmaf(xA[i], w2.y, acc[ph][i][9]);
                    acc[ph][i][10] = fmaf(xA[i], w2.z, acc[ph][i][10]);
                    acc[ph][i][11] = fmaf(xA[i], w2.w, acc[ph][i][11]);
                }
#pragma unroll
                for (int i = 0; i < 4; ++i) {
                    acc[ph][i][0]  = fmaf(xB[i], u0.x, acc[ph][i][0]);
                    acc[ph][i][1]  = fmaf(xB[i], u0.y, acc[ph][i][1]);
                    acc[ph][i][2]  = fmaf(xB[i], u0.z, acc[ph][i][2]);
                    acc[ph][i][3]  = fmaf(xB[i], u0.w, acc[ph][i][3]);
                    acc[ph][i][4]  = fmaf(xB[i], u1.x, acc[ph][i][4]);
                    acc[ph][i][5]  = fmaf(xB[i], u1.y, acc[ph][i][5]);
                    acc[ph][i][6]  = fmaf(xB[i], u1.z, acc[ph][i][6]);
                    acc[ph][i][7]  = fmaf(xB[i], u1.w, acc[ph][i][7]);
                    acc[ph][i][8]  = fmaf(xB[i], u2.x, acc[ph][i][8]);
                    acc[ph][i][9]  = fmaf(xB[i], u2.y, acc[ph][i][9]);
                    acc[ph][i][10] = fmaf(xB[i], u2.z, acc[ph][i][10]);
                    acc[ph][i][11] = fmaf(xB[i], u2.w, acc[ph][i][11]);
                }
            }
        }
    }
    // epilogue: GRU gates; write h_new to global H and (transposed) to sHT
    float bb[12], bh[12];
    {
        float4 b0 = *(const float4*)(biA + tc * 12);
        float4 b1 = *(const float4*)(biA + tc * 12 + 4);
        float4 b2 = *(const float4*)(biA + tc * 12 + 8);
        bb[0] = b0.x; bb[1] = b0.y; bb[2] = b0.z; bb[3] = b0.w;
        bb[4] = b1.x; bb[5] = b1.y; bb[6] = b1.z; bb[7] = b1.w;
        bb[8] = b2.x; bb[9] = b2.y; bb[10] = b2.z; bb[11] = b2.w;
        float4 c0 = *(const float4*)(bh192 + tc * 12);
        float4 c1 = *(const float4*)(bh192 + tc * 12 + 4);
        float4 c2 = *(const float4*)(bh192 + tc * 12 + 8);
        bh[0] = c0.x; bh[1] = c0.y; bh[2] = c0.z; bh[3] = c0.w;
        bh[4] = c1.x; bh[5] = c1.y; bh[6] = c1.z; bh[7] = c1.w;
        bh[8] = c2.x; bh[9] = c2.y; bh[10] = c2.z; bh[11] = c2.w;
    }
#pragma unroll
    for (int i = 0; i < 4; ++i) {
        int n = ntile + tr * 4 + i;
        if (n >= N_NODES) continue;
        float gg[12];
#pragma unroll
        for (int c = 0; c < 12; ++c) gg[c] = acc[1][i][c] + bh[c];
        float4 hv = *(const float4*)(H + (size_t)n * 64 + tc * 4);
        float res[4];
#pragma unroll
        for (int jj = 0; jj < 4; ++jj) {
            int c = jj * 3;
            float r = sigmoidf_(acc[0][i][c] + bb[c] + gg[c]);
            float z = sigmoidf_(acc[0][i][c + 1] + bb[c + 1] + gg[c + 1]);
            float nn = tanhf(acc[0][i][c + 2] + bb[c + 2] + r * gg[c + 2]);
            float hj = (jj == 0) ? hv.x : (jj == 1) ? hv.y : (jj == 2) ? hv.z : hv.w;
            res[jj] = (1.f - z) * nn + z * hj;
        }
        float4 o; o.x = res[0]; o.y = res[1]; o.z = res[2]; o.w = res[3];
        *(float4*)(H + (size_t)n * 64 + tc * 4) = o;
        if (do_trans) {
#pragma unroll
            for (int jj = 0; jj < 4; ++jj)
                sHT[(tc * 4 + jj) * 68 + (tr * 4 + i)] = res[jj];
        }
    }
    // trans tail: buf1 = h_new @ W256 + b256 (4 x 64-col chunks)
    if (do_trans) {
        __syncthreads();   // sHT complete; all phase readers of sW done
        int tc2 = tc * 4;
        for (int mt = 0; mt < 4; ++mt) {
            if (mt) __syncthreads();
#pragma unroll
            for (int i = 0; i < 4; ++i) {
                int idx = i * 256 + tid;            // 0..1023 float4s
                int row = idx >> 4, c4 = (idx & 15) * 4;
                *(float4*)(sW + row * 64 + c4) =
                    *(const float4*)(W256 + (size_t)row * 256 + mt * 64 + c4);
            }
            __syncthreads();
            float4 tacc[4];
#pragma unroll
            for (int i = 0; i < 4; ++i) tacc[i] = make_float4(0.f, 0.f, 0.f, 0.f);
            for (int kk = 0; kk < 64; kk += 2) {
                float4 wA = *(const float4*)(sW + kk * 64 + tc2);
                float4 wB = *(const float4*)(sW + (kk + 1) * 64 + tc2);
                float4 xA4 = *(const float4*)(sHT + kk * 68 + tr * 4);
                float4 xB4 = *(const float4*)(sHT + (kk + 1) * 68 + tr * 4);
                float xA[4] = {xA4.x, xA4.y, xA4.z, xA4.w};
                float xB[4] = {xB4.x, xB4.y, xB4.z, xB4.w};
#pragma unroll
                for (int i = 0; i < 4; ++i) {
                    tacc[i].x = fmaf(xA[i], wA.x, tacc[i].x);
                    tacc[i].y = fmaf(xA[i], wA.y, tacc[i].y);
                    tacc[i].z = fmaf(xA[i], wA.z, tacc[i].z);
                    tacc[i].w = fmaf(xA[i], wA.w, tacc[i].w);
                }
#pragma unroll
                for (int i = 0; i < 4; ++i) {
                    tacc[i].x = fmaf(xB[i], wB.x, tacc[i].x);
                    tacc[i].y = fmaf(xB[i], wB.y, tacc[i].y);
                    tacc[i].z = fmaf(xB[i], wB.z, tacc[i].z);
                    tacc[i].w = fmaf(xB[i], wB.w, tacc[i].w);
                }
            }
            float4 bv = *(const float4*)(b256 + mt * 64 + tc2);
#pragma unroll
            for (int i = 0; i < 4; ++i) {
                int n = ntile + tr * 4 + i;
                if (n < N_NODES) {
                    float4 y;
                    y.x = tacc[i].x + bv.x; y.y = tacc[i].y + bv.y;
                    y.z = tacc[i].z + bv.z; y.w = tacc[i].w + bv.w;
                    *(float4*)(buf1 + (size_t)n * 256 + mt * 64 + tc2) = y;
                }
            }
        }
    }
}

// ---------------- pooling: segmented, atomic-free, multi-block per graph ----------------
__global__ void k_bounds(const int* __restrict__ gid, int* __restrict__ start) {
    int n = blockIdx.x * 256 + threadIdx.x;
    if (n < N_NODES) {
        int g = gid[n];
        if (n == 0) {
            for (int x = 0; x <= g; ++x) start[x] = 0;
        } else {
            int pg = gid[n - 1];
            for (int x = pg + 1; x <= g; ++x) start[x] = n;
        }
        if (n == N_NODES - 1) {
            for (int x = g + 1; x <= NGRAPH; ++x) start[x] = N_NODES;
        }
    }
}

__global__ void k_gate2(const float* __restrict__ H, const float* __restrict__ H0,
                        const float* __restrict__ gW, const float* __restrict__ gb,
                        float* __restrict__ gate) {
    int l = threadIdx.x & 63;
    int n = blockIdx.x * 4 + (threadIdx.x >> 6);
    float v = H[(size_t)n * 64 + l] * gW[l] + H0[(size_t)n * 64 + l] * gW[64 + l];
    for (int off = 32; off > 0; off >>= 1) v += __shfl_xor(v, off, 64);
    if (l == 0) gate[n] = v + gb[0];
}

__global__ __launch_bounds__(64) void k_poolA(const float* __restrict__ gate,
                                              const int* __restrict__ start,
                                              float* __restrict__ pmax) {
    int g = blockIdx.x, s = blockIdx.y;
    int beg = start[g], len = start[g + 1] - beg;
    int sb = beg + (int)((long long)len * s / PS);
    int se = beg + (int)((long long)len * (s + 1) / PS);
    float m = -INFINITY;
    for (int n = sb + threadIdx.x; n < se; n += 64) m = fmaxf(m, gate[n]);
    for (int off = 32; off > 0; off >>= 1) m = fmaxf(m, __shfl_xor(m, off, 64));
    if (threadIdx.x == 0) pmax[g * PS + s] = m;
}

__global__ void k_poolB(const float* __restrict__ pmax, float* __restrict__ gm) {
    int g = threadIdx.x;  // 64 threads
    float m = -INFINITY;
    for (int s = 0; s < PS; ++s) m = fmaxf(m, pmax[g * PS + s]);
    if (!isfinite(m)) m = 0.0f;   // reference's empty-graph guard
    gm[g] = m;
}

__global__ __launch_bounds__(256) void k_poolC(const float* __restrict__ H,
                                               const float* __restrict__ H0,
                                               const float* __restrict__ gate,
                                               const int* __restrict__ start,
                                               const float* __restrict__ gm,
                                               float* __restrict__ pnum,
                                               float* __restrict__ pden) {
    int g = blockIdx.x, s = blockIdx.y;
    int beg = start[g], len = start[g + 1] - beg;
    int sb = beg + (int)((long long)len * s / PS);
    int se = beg + (int)((long long)len * (s + 1) / PS);
    int t = threadIdx.x;
    int lane = t & 63, wave = t >> 6;
    float m = gm[g];
    __shared__ float shh[4][64], sh0[4][64], ses[4];
    float ah = 0.f, ah0 = 0.f, es = 0.f;
    for (int n = sb + wave; n < se; n += 4) {
        float e = expf(gate[n] - m);
        es += e;
        ah  += e * H [(size_t)n * 64 + lane];
        ah0 += e * H0[(size_t)n * 64 + lane];
    }
    shh[wave][lane] = ah; sh0[wave][lane] = ah0;
    if (lane == 0) ses[wave] = es;
    __syncthreads();
    if (wave == 0) {
        float r  = shh[0][lane] + shh[1][lane] + shh[2][lane] + shh[3][lane];
        float r0 = sh0[0][lane] + sh0[1][lane] + sh0[2][lane] + sh0[3][lane];
        int base = (g * PS + s) * 128;
        pnum[base + lane]      = r;
        pnum[base + 64 + lane] = r0;
        if (lane == 0) pden[g * PS + s] = ses[0] + ses[1] + ses[2] + ses[3];
    }
}

__global__ __launch_bounds__(128) void k_poolD(const float* __restrict__ pnum,
                                               const float* __restrict__ pden,
                                               float* __restrict__ ro) {
    int g = blockIdx.x;
    int c = threadIdx.x;
    float den = 0.f;
    for (int s = 0; s < PS; ++s) den += pden[g * PS + s];
    float nu = 0.f;
    for (int s = 0; s < PS; ++s) nu += pnum[(g * PS + s) * 128 + c];
    ro[g * 128 + c] = (den > 0.f) ? nu / den : 0.f;
}

__global__ void k_logits(const float* __restrict__ ro, const float* __restrict__ oW,
                         const float* __restrict__ ob, float* __restrict__ out) {
    int t = threadIdx.x;
    int b = t >> 1;
    int c = t & 1;
    float acc = ob[c];
    for (int k = 0; k < 128; ++k) acc = fmaf(ro[b * 128 + k], oW[k * 2 + c], acc);
    out[b * 2 + c] = acc;
}

extern "C" void kernel_launch(void* const* d_in, const int* in_sizes, int n_in,
                              void* d_out, int out_size, void* d_ws, size_t ws_size,
                              hipStream_t stream) {
    (void)in_sizes; (void)n_in; (void)out_size; (void)ws_size;
    const float* ann = (const float*)d_in[0];
    const int* src   = (const int*)d_in[1];
    const int* dst   = (const int*)d_in[2];
    const int* ety   = (const int*)d_in[3];
    const int* gid   = (const int*)d_in[4];
    const float* rW  = (const float*)d_in[5];
    const float* rb  = (const float*)d_in[6];
    const float* eW  = (const float*)d_in[7];
    const float* eb  = (const float*)d_in[8];
    const float* Wi  = (const float*)d_in[9];
    const float* Bi  = (const float*)d_in[10];
    const float* Wh  = (const float*)d_in[11];
    const float* Bh  = (const float*)d_in[12];
    const float* gW  = (const float*)d_in[13];
    const float* gb  = (const float*)d_in[14];
    const float* oW  = (const float*)d_in[15];
    const float* ob  = (const float*)d_in[16];
    float* out = (float*)d_out;

    char* p = (char*)d_ws;
    auto take = [&](size_t nbytes) -> void* {
        void* r = (void*)p;
        p += (nbytes + 255) & ~((size_t)255);
        return r;
    };
    float* h0      = (float*)take((size_t)N_NODES * 64 * 4);
    float* h       = (float*)take((size_t)N_NODES * 64 * 4);
    float* abuf    = (float*)take((size_t)N_NODES * 64 * 4);
    float* buf1    = (float*)take((size_t)N_NODES * 256 * 4);   // trans only [N][4*64]
    float* W256    = (float*)take(64 * 256 * 4);
    float* b256    = (float*)take(256 * 4);
    float* Wh192   = (float*)take(64 * 192 * 4);
    float* bh192   = (float*)take(192 * 4);
    float* WiA     = (float*)take(64 * 192 * 4);
    float* biA     = (float*)take(192 * 4);
    int* deg       = (int*)take((size_t)N_NODES * 4);
    int* cur       = (int*)take((size_t)N_NODES * 4);
    int* rs        = (int*)take((size_t)(N_NODES + 1) * 4);
    int* part      = (int*)take(512);
    int* colidx    = (int*)take((size_t)N_EDGES * 4);
    float* gate    = (float*)take((size_t)N_NODES * 4);
    int* start     = (int*)take((size_t)(NGRAPH + 1) * 4);
    float* pmax    = (float*)take(NGRAPH * PS * 4);
    float* gm      = (float*)take(NGRAPH * 4);
    float* pnum    = (float*)take((size_t)NGRAPH * PS * 128 * 4);
    float* pden    = (float*)take(NGRAPH * PS * 4);
    float* ro      = (float*)take(NGRAPH * 128 * 4);

    // ---- CSR build (by dst)
    hipMemsetAsync(deg, 0, (size_t)N_NODES * 4, stream);
    hipMemsetAsync(cur, 0, (size_t)N_NODES * 4, stream);
    k_count<<<(N_EDGES + 255) / 256, 256, 0, stream>>>(dst, deg);
    int nb = (N_NODES + 1023) / 1024;  // 98
    k_scan1<<<nb, 256, 0, stream>>>(deg, rs, part);
    k_scan2<<<1, 64, 0, stream>>>(part, rs, nb);
    k_scan3<<<(N_NODES + 255) / 256, 256, 0, stream>>>(rs, part);
    k_fill<<<(N_EDGES + 255) / 256, 256, 0, stream>>>(src, dst, ety, rs, cur, colidx);

    // ---- weight prep + graph bounds
    k_prep2<<<112, 256, 0, stream>>>(Wh, Bh, eW, eb, Wi, Bi, W256, b256, Wh192, bh192, WiA, biA);
    k_bounds<<<(N_NODES + 255) / 256, 256, 0, stream>>>(gid, start);

    int ntiles = (N_NODES + 127) / 128;  // 782

    // ---- reduce layer: h = h0 = ann @ rW + rb (K-pipelined)
    k_gemm_red<<<ntiles, 256, 0, stream>>>(ann, rW, rb, h, h0);

    // ---- pre-loop trans of h0 into buf1
    k_gemm<<<dim3(4, ntiles), 256, 0, stream>>>(h, 64, 64, W256, 256, b256,
                                                buf1, nullptr, 256);

    // ---- message-passing steps: aggregate (2-node waves) + fused GRU/trans
    for (int s = 0; s < NSTEPS; ++s) {
        k_aggregate<<<N_NODES / 8, 256, 0, stream>>>(buf1, rs, colidx, abuf);
        k_gruF3<<<(N_NODES + 63) / 64, 256, 0, stream>>>(abuf, WiA, biA, Wh192, bh192,
                                                         W256, b256, h, buf1,
                                                         (s < NSTEPS - 1) ? 1 : 0);
    }

    // ---- pooling + classifier (atomic-free, multi-block)
    k_gate2<<<N_NODES / 4, 256, 0, stream>>>(h, h0, gW, gb, gate);
    k_poolA<<<dim3(NGRAPH, PS), 64, 0, stream>>>(gate, start, pmax);
    k_poolB<<<1, 64, 0, stream>>>(pmax, gm);
    k_poolC<<<dim3(NGRAPH, PS), 256, 0, stream>>>(h, h0, gate, start, gm, pnum, pden);
    k_poolD<<<NGRAPH, 128, 0, stream>>>(pnum, pden, ro);
    k_logits<<<1, 128, 0, stream>>>(ro, oW, ob, out);
}

// Round 9
// 1548.950 us; speedup vs baseline: 1.1693x; 1.0172x over previous
//
#include <hip/hip_runtime.h>
#include <cstdint>
#include <cstddef>

#define N_NODES 100000
#define N_EDGES 1200000
#define ASIZE 256
#define HSIZE 64
#define NTYPES 4
#define NSTEPS 6
#define NGRAPH 64
#define PS 16   // pooling splits per graph

static __device__ __forceinline__ float sigmoidf_(float x) { return 1.0f / (1.0f + expf(-x)); }

// ---------------- CSR build (by dst) ----------------
__global__ void k_count(const int* __restrict__ dst, int* __restrict__ deg) {
    int e = blockIdx.x * 256 + threadIdx.x;
    if (e < N_EDGES) atomicAdd(&deg[dst[e]], 1);
}

__global__ void k_scan1(const int* __restrict__ deg, int* __restrict__ rs, int* __restrict__ part) {
    __shared__ int sh[256];
    int t = threadIdx.x;
    int base = blockIdx.x * 1024 + t * 4;
    int v0 = (base + 0 < N_NODES) ? deg[base + 0] : 0;
    int v1 = (base + 1 < N_NODES) ? deg[base + 1] : 0;
    int v2 = (base + 2 < N_NODES) ? deg[base + 2] : 0;
    int v3 = (base + 3 < N_NODES) ? deg[base + 3] : 0;
    int s = v0 + v1 + v2 + v3;
    sh[t] = s;
    __syncthreads();
    for (int off = 1; off < 256; off <<= 1) {
        int x = (t >= off) ? sh[t - off] : 0;
        __syncthreads();
        sh[t] += x;
        __syncthreads();
    }
    int excl = sh[t] - s;
    if (t == 255) part[blockIdx.x] = sh[255];
    if (base + 0 < N_NODES) rs[base + 0] = excl;
    if (base + 1 < N_NODES) rs[base + 1] = excl + v0;
    if (base + 2 < N_NODES) rs[base + 2] = excl + v0 + v1;
    if (base + 3 < N_NODES) rs[base + 3] = excl + v0 + v1 + v2;
}

__global__ void k_scan2(int* __restrict__ part, int* __restrict__ rs, int nb) {
    if (threadIdx.x == 0 && blockIdx.x == 0) {
        int run = 0;
        for (int i = 0; i < nb; ++i) { int v = part[i]; part[i] = run; run += v; }
        rs[N_NODES] = run;
    }
}

__global__ void k_scan3(int* __restrict__ rs, const int* __restrict__ part) {
    int i = blockIdx.x * 256 + threadIdx.x;
    if (i < N_NODES) rs[i] += part[i >> 10];
}

// colidx holds a precomputed float-offset into buf1 ([N][256] trans-only): src*256 + ety*64
__global__ void k_fill(const int* __restrict__ src, const int* __restrict__ dst,
                       const int* __restrict__ ety, const int* __restrict__ rs,
                       int* __restrict__ cur, int* __restrict__ colidx) {
    int e = blockIdx.x * 256 + threadIdx.x;
    if (e < N_EDGES) {
        int d = dst[e];
        int pos = rs[d] + atomicAdd(&cur[d], 1);
        colidx[pos] = src[e] * 256 + ety[e] * 64;
    }
}

// ---------------- weight prep ----------------
__global__ void k_prep2(const float* __restrict__ Wh, const float* __restrict__ Bh,
                        const float* __restrict__ eW, const float* __restrict__ eb,
                        const float* __restrict__ Wi, const float* __restrict__ Bi,
                        float* __restrict__ W256, float* __restrict__ b256,
                        float* __restrict__ Wh192, float* __restrict__ bh192,
                        float* __restrict__ WiA, float* __restrict__ biA) {
    int idx = blockIdx.x * 256 + threadIdx.x;
    if (idx < 64 * 256) {
        int k = idx / 256, c = idx % 256;
        W256[idx] = eW[(size_t)(c >> 6) * 4096 + k * 64 + (c & 63)];
    }
    if (idx < 64 * 192) {
        int k = idx / 192, m = idx % 192;
        int j = m / 3, g = m % 3;
        WiA[idx]   = Wi[(g * 64 + j) * 64 + k];
        Wh192[idx] = Wh[(g * 64 + j) * 64 + k];
    }
    if (idx < 256) b256[idx] = eb[idx];
    if (idx < 192) {
        biA[idx]   = Bi[(idx % 3) * 64 + idx / 3];
        bh192[idx] = Bh[(idx % 3) * 64 + idx / 3];
    }
}

// ---------------- generic tiled GEMM (used once: pre-loop trans of h0) ----------------
__global__ __launch_bounds__(256) void k_gemm(const float* __restrict__ X, int ldx, int K,
                                              const float* __restrict__ W, int ldw,
                                              const float* __restrict__ bias,
                                              float* __restrict__ Y, float* __restrict__ Y2,
                                              int M) {
    __shared__ float sX[128 * 66];
    __shared__ float sW[64 * 64];
    int tid = threadIdx.x;
    int mtile = blockIdx.x * 64;
    int ntile = blockIdx.y * 128;
    int tc4 = (tid & 15) * 4;
    int tr = tid >> 4;
    float4 acc[8];
#pragma unroll
    for (int i = 0; i < 8; ++i) acc[i] = make_float4(0.f, 0.f, 0.f, 0.f);

    int nkc = K >> 6;
    for (int kc = 0; kc < nkc; ++kc) {
        if (kc) __syncthreads();
#pragma unroll
        for (int i = 0; i < 8; ++i) {
            int lin4 = (i * 256 + tid) * 4;
            int nl = lin4 >> 6, kk = lin4 & 63;
            int n = ntile + nl;
            float4 v = make_float4(0.f, 0.f, 0.f, 0.f);
            if (n < N_NODES) v = *(const float4*)(X + (size_t)n * ldx + kc * 64 + kk);
            float* d = sX + nl * 66 + kk;
            d[0] = v.x; d[1] = v.y; d[2] = v.z; d[3] = v.w;
        }
#pragma unroll
        for (int i = 0; i < 4; ++i) {
            int lin4 = (i * 256 + tid) * 4;
            int kk = lin4 >> 6, c = lin4 & 63;
            float4 v = *(const float4*)(W + (size_t)(kc * 64 + kk) * ldw + mtile + c);
            *(float4*)(sW + kk * 64 + c) = v;
        }
        __syncthreads();
        const float* xr = sX + tr * 8 * 66;
        const float* wr = sW + tc4;
        for (int kk = 0; kk < 64; kk += 2) {
            float4 wA = *(const float4*)(wr + kk * 64);
            float4 wB = *(const float4*)(wr + (kk + 1) * 64);
            float xA[8], xB[8];
#pragma unroll
            for (int i = 0; i < 8; ++i) { xA[i] = xr[i * 66 + kk]; xB[i] = xr[i * 66 + kk + 1]; }
#pragma unroll
            for (int i = 0; i < 8; ++i) {
                acc[i].x = fmaf(xA[i], wA.x, acc[i].x);
                acc[i].y = fmaf(xA[i], wA.y, acc[i].y);
                acc[i].z = fmaf(xA[i], wA.z, acc[i].z);
                acc[i].w = fmaf(xA[i], wA.w, acc[i].w);
            }
#pragma unroll
            for (int i = 0; i < 8; ++i) {
                acc[i].x = fmaf(xB[i], wB.x, acc[i].x);
                acc[i].y = fmaf(xB[i], wB.y, acc[i].y);
                acc[i].z = fmaf(xB[i], wB.z, acc[i].z);
                acc[i].w = fmaf(xB[i], wB.w, acc[i].w);
            }
        }
    }
    float4 bv = *(const float4*)(bias + mtile + tc4);
#pragma unroll
    for (int i = 0; i < 8; ++i) {
        int n = ntile + tr * 8 + i;
        if (n < N_NODES) {
            float4 y;
            y.x = acc[i].x + bv.x; y.y = acc[i].y + bv.y;
            y.z = acc[i].z + bv.z; y.w = acc[i].w + bv.w;
            *(float4*)(Y + (size_t)n * M + mtile + tc4) = y;
            if (Y2) *(float4*)(Y2 + (size_t)n * M + mtile + tc4) = y;
        }
    }
}

// ---------------- reduce GEMM: h = h0 = ann[N][256] @ rW[256][64] + rb ----------------
// 64-node tiles (was 128): LDS 50.7KB -> 33.3KB, ~60 VGPR => 4 blocks/CU (16 waves/CU,
// +33% TLP for the 102MB ann stream) and 2x blocks (1563) overlapping across barriers.
// K-pipelined register prefetch as before. Per-output fma chain (kc,kk ascending, wA then
// wB) identical to the 128-tile version -> bit-exact.
__global__ __launch_bounds__(256) void k_gemm_red(const float* __restrict__ X,
                                                  const float* __restrict__ W,
                                                  const float* __restrict__ bias,
                                                  float* __restrict__ Y,
                                                  float* __restrict__ Y2) {
    __shared__ float sX[64 * 66];
    __shared__ float sW[64 * 64];
    int tid = threadIdx.x;
    int ntile = blockIdx.x * 64;
    int tc4 = (tid & 15) * 4;
    int tr = tid >> 4;           // 0..15, 4 nodes each
    int swr = tid >> 4;
    int swc = (tid & 15) * 4;

    float4 acc[4];
#pragma unroll
    for (int i = 0; i < 4; ++i) acc[i] = make_float4(0.f, 0.f, 0.f, 0.f);

    float4 xreg[4];
    float4 wreg[4];
#pragma unroll
    for (int i = 0; i < 4; ++i) {
        int lin4 = (i * 256 + tid) * 4;
        int nl = lin4 >> 6, kk = lin4 & 63;
        int n = ntile + nl;
        float4 v = make_float4(0.f, 0.f, 0.f, 0.f);
        if (n < N_NODES) v = *(const float4*)(X + (size_t)n * 256 + kk);
        xreg[i] = v;
    }
#pragma unroll
    for (int i = 0; i < 4; ++i)
        wreg[i] = *(const float4*)(W + (size_t)(i * 16 + swr) * 64 + swc);

    for (int kc = 0; kc < 4; ++kc) {
#pragma unroll
        for (int i = 0; i < 4; ++i) {
            int lin4 = (i * 256 + tid) * 4;
            int nl = lin4 >> 6, kk = lin4 & 63;
            float* d = sX + nl * 66 + kk;
            d[0] = xreg[i].x; d[1] = xreg[i].y; d[2] = xreg[i].z; d[3] = xreg[i].w;
        }
#pragma unroll
        for (int i = 0; i < 4; ++i)
            *(float4*)(sW + (i * 16 + swr) * 64 + swc) = wreg[i];
        __syncthreads();
        if (kc < 3) {
#pragma unroll
            for (int i = 0; i < 4; ++i) {
                int lin4 = (i * 256 + tid) * 4;
                int nl = lin4 >> 6, kk = lin4 & 63;
                int n = ntile + nl;
                float4 v = make_float4(0.f, 0.f, 0.f, 0.f);
                if (n < N_NODES) v = *(const float4*)(X + (size_t)n * 256 + (kc + 1) * 64 + kk);
                xreg[i] = v;
            }
#pragma unroll
            for (int i = 0; i < 4; ++i)
                wreg[i] = *(const float4*)(W + (size_t)((kc + 1) * 64 + i * 16 + swr) * 64 + swc);
        }
        const float* xr = sX + tr * 4 * 66;
        const float* wrp = sW + tc4;
        for (int kk = 0; kk < 64; kk += 2) {
            float4 wA = *(const float4*)(wrp + kk * 64);
            float4 wB = *(const float4*)(wrp + (kk + 1) * 64);
            float xA[4], xB[4];
#pragma unroll
            for (int i = 0; i < 4; ++i) { xA[i] = xr[i * 66 + kk]; xB[i] = xr[i * 66 + kk + 1]; }
#pragma unroll
            for (int i = 0; i < 4; ++i) {
                acc[i].x = fmaf(xA[i], wA.x, acc[i].x);
                acc[i].y = fmaf(xA[i], wA.y, acc[i].y);
                acc[i].z = fmaf(xA[i], wA.z, acc[i].z);
                acc[i].w = fmaf(xA[i], wA.w, acc[i].w);
            }
#pragma unroll
            for (int i = 0; i < 4; ++i) {
                acc[i].x = fmaf(xB[i], wB.x, acc[i].x);
                acc[i].y = fmaf(xB[i], wB.y, acc[i].y);
                acc[i].z = fmaf(xB[i], wB.z, acc[i].z);
                acc[i].w = fmaf(xB[i], wB.w, acc[i].w);
            }
        }
        if (kc < 3) __syncthreads();
    }
    float4 bv = *(const float4*)(bias + tc4);
#pragma unroll
    for (int i = 0; i < 4; ++i) {
        int n = ntile + tr * 4 + i;
        if (n < N_NODES) {
            float4 y;
            y.x = acc[i].x + bv.x; y.y = acc[i].y + bv.y;
            y.z = acc[i].z + bv.z; y.w = acc[i].w + bv.w;
            *(float4*)(Y + (size_t)n * 64 + tc4) = y;
            *(float4*)(Y2 + (size_t)n * 64 + tc4) = y;
        }
    }
}

// ---------------- edge aggregate: a[n] = sum of incoming trans rows from buf1 ----------------
// (exact R4 form — proven best: 1 node/wave, masked final batch, max occupancy.
// R8 bracketing: fewer waves + more ILP was WORSE; this is the TLP-optimal point.)
__global__ void k_aggregate(const float* __restrict__ buf1, const int* __restrict__ rs,
                            const int* __restrict__ colidx, float* __restrict__ a) {
    int l = threadIdx.x & 63;
    int n = blockIdx.x * 4 + (threadIdx.x >> 6);  // 25000 blocks * 4 = N exactly
    int sub = l >> 4;            // edge slot within group of 4
    int kq = (l & 15) * 4;       // k quad handled by this lane
    int beg = rs[n], end = rs[n + 1];             // wave-uniform
    int deg = end - beg;
    int c4end = beg + (deg & ~3);                 // end of 4-aligned main portion
    float4 acc = make_float4(0.f, 0.f, 0.f, 0.f);
    int s = beg;
    for (; s + 31 < c4end; s += 32) {
        int c0 = colidx[s + sub];
        int c1 = colidx[s + 4 + sub];
        int c2 = colidx[s + 8 + sub];
        int c3 = colidx[s + 12 + sub];
        int c4 = colidx[s + 16 + sub];
        int c5 = colidx[s + 20 + sub];
        int c6 = colidx[s + 24 + sub];
        int c7 = colidx[s + 28 + sub];
        float4 v0 = *(const float4*)(buf1 + (size_t)c0 + kq);
        float4 v1 = *(const float4*)(buf1 + (size_t)c1 + kq);
        float4 v2 = *(const float4*)(buf1 + (size_t)c2 + kq);
        float4 v3 = *(const float4*)(buf1 + (size_t)c3 + kq);
        float4 v4 = *(const float4*)(buf1 + (size_t)c4 + kq);
        float4 v5 = *(const float4*)(buf1 + (size_t)c5 + kq);
        float4 v6 = *(const float4*)(buf1 + (size_t)c6 + kq);
        float4 v7 = *(const float4*)(buf1 + (size_t)c7 + kq);
        acc.x += v0.x; acc.y += v0.y; acc.z += v0.z; acc.w += v0.w;
        acc.x += v1.x; acc.y += v1.y; acc.z += v1.z; acc.w += v1.w;
        acc.x += v2.x; acc.y += v2.y; acc.z += v2.z; acc.w += v2.w;
        acc.x += v3.x; acc.y += v3.y; acc.z += v3.z; acc.w += v3.w;
        acc.x += v4.x; acc.y += v4.y; acc.z += v4.z; acc.w += v4.w;
        acc.x += v5.x; acc.y += v5.y; acc.z += v5.z; acc.w += v5.w;
        acc.x += v6.x; acc.y += v6.y; acc.z += v6.z; acc.w += v6.w;
        acc.x += v7.x; acc.y += v7.y; acc.z += v7.z; acc.w += v7.w;
    }
    {
        int nv = (c4end - s) >> 2;
        float4 vv[7];
#pragma unroll
        for (int k = 0; k < 7; ++k) {
            if (k < nv) {
                int c = colidx[s + k * 4 + sub];
                vv[k] = *(const float4*)(buf1 + (size_t)c + kq);
            }
        }
#pragma unroll
        for (int k = 0; k < 7; ++k) {
            if (k < nv) {
                acc.x += vv[k].x; acc.y += vv[k].y; acc.z += vv[k].z; acc.w += vv[k].w;
            }
        }
        s += nv * 4;
    }
    for (; s < end; ++s) {
        if (sub == 0) {
            int c = colidx[s];
            float4 v = *(const float4*)(buf1 + (size_t)c + kq);
            acc.x += v.x; acc.y += v.y; acc.z += v.z; acc.w += v.w;
        }
    }
    float4 t;
    t.x = acc.x + __shfl_xor(acc.x, 16, 64);
    t.y = acc.y + __shfl_xor(acc.y, 16, 64);
    t.z = acc.z + __shfl_xor(acc.z, 16, 64);
    t.w = acc.w + __shfl_xor(acc.w, 16, 64);
    float4 r;
    r.x = t.x + __shfl_xor(t.x, 32, 64);
    r.y = t.y + __shfl_xor(t.y, 32, 64);
    r.z = t.z + __shfl_xor(t.z, 32, 64);
    r.w = t.w + __shfl_xor(t.w, 32, 64);
    if (sub == 0) *(float4*)(a + (size_t)n * 64 + kq) = r;
}

// ---------------- fused: gi-GEMM + gh-GEMM + GRU + trans-GEMM for next step ----------------
// (exact R4 k_gruF3 — proven 143us: sW staged in LDS, transposed-X b128 reads)
__global__ __launch_bounds__(256) void k_gruF3(const float* __restrict__ A,
                                               const float* __restrict__ WiA,
                                               const float* __restrict__ biA,
                                               const float* __restrict__ Wh192,
                                               const float* __restrict__ bh192,
                                               const float* __restrict__ W256,
                                               const float* __restrict__ b256,
                                               float* __restrict__ H,
                                               float* __restrict__ buf1,
                                               int do_trans) {
    __shared__ float sXT[32 * 68];   // [k][node], stride 68 (16B-aligned rows)
    __shared__ float sW[32 * 192];   // gi/gh W chunks; reused as [64][64] for trans chunks
    __shared__ float sHT[64 * 68];   // h_new transposed [k][node]
    int tid = threadIdx.x;
    int ntile = blockIdx.x * 64;
    int tc = tid & 15;
    int tr = tid >> 4;
    float acc[2][4][12];
#pragma unroll
    for (int p = 0; p < 2; ++p)
#pragma unroll
        for (int i = 0; i < 4; ++i)
#pragma unroll
            for (int c = 0; c < 12; ++c) acc[p][i][c] = 0.f;

#pragma unroll
    for (int ph = 0; ph < 2; ++ph) {
        const float* Xsrc = (ph == 0) ? A : H;
        const float* Wsrc = (ph == 0) ? WiA : Wh192;
        for (int kc = 0; kc < 2; ++kc) {
            if (ph || kc) __syncthreads();
            // stage X transposed: 64 nodes x 32 k
#pragma unroll
            for (int i = 0; i < 2; ++i) {
                int lin = i * 256 + tid;             // 0..511 float4s
                int nl = lin >> 3;                   // node 0..63
                int kk = (lin & 7) * 4;              // k 0..28
                int n = ntile + nl;
                float4 v = make_float4(0.f, 0.f, 0.f, 0.f);
                if (n < N_NODES) v = *(const float4*)(Xsrc + (size_t)n * 64 + kc * 32 + kk);
                sXT[(kk + 0) * 68 + nl] = v.x;
                sXT[(kk + 1) * 68 + nl] = v.y;
                sXT[(kk + 2) * 68 + nl] = v.z;
                sXT[(kk + 3) * 68 + nl] = v.w;
            }
            {
                int kk = tid >> 3, c = (tid & 7) * 24;
                const float* srcp = Wsrc + (size_t)(kc * 32 + kk) * 192 + c;
                float* d = sW + kk * 192 + c;
#pragma unroll
                for (int u = 0; u < 6; ++u) *(float4*)(d + 4 * u) = *(const float4*)(srcp + 4 * u);
            }
            __syncthreads();
            const float* wr = sW + tc * 12;
            for (int kk = 0; kk < 32; kk += 2) {
                float4 w0 = *(const float4*)(wr + kk * 192);
                float4 w1 = *(const float4*)(wr + kk * 192 + 4);
                float4 w2 = *(const float4*)(wr + kk * 192 + 8);
                float4 u0 = *(const float4*)(wr + (kk + 1) * 192);
                float4 u1 = *(const float4*)(wr + (kk + 1) * 192 + 4);
                float4 u2 = *(const float4*)(wr + (kk + 1) * 192 + 8);
                float4 xA4 = *(const float4*)(sXT + kk * 68 + tr * 4);
                float4 xB4 = *(const float4*)(sXT + (kk + 1) * 68 + tr * 4);
                float xA[4] = {xA4.x, xA4.y, xA4.z, xA4.w};
                float xB[4] = {xB4.x, xB4.y, xB4.z, xB4.w};
#pragma unroll
                for (int i = 0; i < 4; ++i) {
                    acc[ph][i][0]  = fmaf(xA[i], w0.x, acc[ph][i][0]);
                    acc[ph][i][1]  = fmaf(xA[i], w0.y, acc[ph][i][1]);
                    acc[ph][i][2]  = fmaf(xA[i], w0.z, acc[ph][i][2]);
                    acc[ph][i][3]  = fmaf(xA[i], w0.w, acc[ph][i][3]);
                    acc[ph][i][4]  = fmaf(xA[i], w1.x, acc[ph][i][4]);
                    acc[ph][i][5]  = fmaf(xA[i], w1.y, acc[ph][i][5]);
                    acc[ph][i][6]  = fmaf(xA[i], w1.z, acc[ph][i][6]);
                    acc[ph][i][7]  = fmaf(xA[i], w1.w, acc[ph][i][7]);
                    acc[ph][i][8]  = fmaf(xA[i], w2.x, acc[ph][i][8]);
                    acc[ph][i][9]  = fmaf(xA[i], w2.y, acc[ph][i][9]);
                    acc[ph][i][10] = fmaf(xA[i], w2.z, acc[ph][i][10]);
                    acc[ph][i][11] = fmaf(xA[i], w2.w, acc[ph][i][11]);
                }
#pragma unroll
                for (int i = 0; i < 4; ++i) {
                    acc[ph][i][0]  = fmaf(xB[i], u0.x, acc[ph][i][0]);
                    acc[ph][i][1]  = fmaf(xB[i], u0.y, acc[ph][i][1]);
                    acc[ph][i][2]  = fmaf(xB[i], u0.z, acc[ph][i][2]);
                    acc[ph][i][3]  = fmaf(xB[i], u0.w, acc[ph][i][3]);
                    acc[ph][i][4]  = fmaf(xB[i], u1.x, acc[ph][i][4]);
                    acc[ph][i][5]  = fmaf(xB[i], u1.y, acc[ph][i][5]);
                    acc[ph][i][6]  = fmaf(xB[i], u1.z, acc[ph][i][6]);
                    acc[ph][i][7]  = fmaf(xB[i], u1.w, acc[ph][i][7]);
                    acc[ph][i][8]  = fmaf(xB[i], u2.x, acc[ph][i][8]);
                    acc[ph][i][9]  = fmaf(xB[i], u2.y, acc[ph][i][9]);
                    acc[ph][i][10] = fmaf(xB[i], u2.z, acc[ph][i][10]);
                    acc[ph][i][11] = fmaf(xB[i], u2.w, acc[ph][i][11]);
                }
            }
        }
    }
    // epilogue: GRU gates; write h_new to global H and (transposed) to sHT
    float bb[12], bh[12];
    {
        float4 b0 = *(const float4*)(biA + tc * 12);
        float4 b1 = *(const float4*)(biA + tc * 12 + 4);
        float4 b2 = *(const float4*)(biA + tc * 12 + 8);
        bb[0] = b0.x; bb[1] = b0.y; bb[2] = b0.z; bb[3] = b0.w;
        bb[4] = b1.x; bb[5] = b1.y; bb[6] = b1.z; bb[7] = b1.w;
        bb[8] = b2.x; bb[9] = b2.y; bb[10] = b2.z; bb[11] = b2.w;
        float4 c0 = *(const float4*)(bh192 + tc * 12);
        float4 c1 = *(const float4*)(bh192 + tc * 12 + 4);
        float4 c2 = *(const float4*)(bh192 + tc * 12 + 8);
        bh[0] = c0.x; bh[1] = c0.y; bh[2] = c0.z; bh[3] = c0.w;
        bh[4] = c1.x; bh[5] = c1.y; bh[6] = c1.z; bh[7] = c1.w;
        bh[8] = c2.x; bh[9] = c2.y; bh[10] = c2.z; bh[11] = c2.w;
    }
#pragma unroll
    for (int i = 0; i < 4; ++i) {
        int n = ntile + tr * 4 + i;
        if (n >= N_NODES) continue;
        float gg[12];
#pragma unroll
        for (int c = 0; c < 12; ++c) gg[c] = acc[1][i][c] + bh[c];
        float4 hv = *(const float4*)(H + (size_t)n * 64 + tc * 4);
        float res[4];
#pragma unroll
        for (int jj = 0; jj < 4; ++jj) {
            int c = jj * 3;
            float r = sigmoidf_(acc[0][i][c] + bb[c] + gg[c]);
            float z = sigmoidf_(acc[0][i][c + 1] + bb[c + 1] + gg[c + 1]);
            float nn = tanhf(acc[0][i][c + 2] + bb[c + 2] + r * gg[c + 2]);
            float hj = (jj == 0) ? hv.x : (jj == 1) ? hv.y : (jj == 2) ? hv.z : hv.w;
            res[jj] = (1.f - z) * nn + z * hj;
        }
        float4 o; o.x = res[0]; o.y = res[1]; o.z = res[2]; o.w = res[3];
        *(float4*)(H + (size_t)n * 64 + tc * 4) = o;
        if (do_trans) {
#pragma unroll
            for (int jj = 0; jj < 4; ++jj)
                sHT[(tc * 4 + jj) * 68 + (tr * 4 + i)] = res[jj];
        }
    }
    // trans tail: buf1 = h_new @ W256 + b256 (4 x 64-col chunks)
    if (do_trans) {
        __syncthreads();   // sHT complete; all phase readers of sW done
        int tc2 = tc * 4;
        for (int mt = 0; mt < 4; ++mt) {
            if (mt) __syncthreads();
#pragma unroll
            for (int i = 0; i < 4; ++i) {
                int idx = i * 256 + tid;            // 0..1023 float4s
                int row = idx >> 4, c4 = (idx & 15) * 4;
                *(float4*)(sW + row * 64 + c4) =
                    *(const float4*)(W256 + (size_t)row * 256 + mt * 64 + c4);
            }
            __syncthreads();
            float4 tacc[4];
#pragma unroll
            for (int i = 0; i < 4; ++i) tacc[i] = make_float4(0.f, 0.f, 0.f, 0.f);
            for (int kk = 0; kk < 64; kk += 2) {
                float4 wA = *(const float4*)(sW + kk * 64 + tc2);
                float4 wB = *(const float4*)(sW + (kk + 1) * 64 + tc2);
                float4 xA4 = *(const float4*)(sHT + kk * 68 + tr * 4);
                float4 xB4 = *(const float4*)(sHT + (kk + 1) * 68 + tr * 4);
                float xA[4] = {xA4.x, xA4.y, xA4.z, xA4.w};
                float xB[4] = {xB4.x, xB4.y, xB4.z, xB4.w};
#pragma unroll
                for (int i = 0; i < 4; ++i) {
                    tacc[i].x = fmaf(xA[i], wA.x, tacc[i].x);
                    tacc[i].y = fmaf(xA[i], wA.y, tacc[i].y);
                    tacc[i].z = fmaf(xA[i], wA.z, tacc[i].z);
                    tacc[i].w = fmaf(xA[i], wA.w, tacc[i].w);
                }
#pragma unroll
                for (int i = 0; i < 4; ++i) {
                    tacc[i].x = fmaf(xB[i], wB.x, tacc[i].x);
                    tacc[i].y = fmaf(xB[i], wB.y, tacc[i].y);
                    tacc[i].z = fmaf(xB[i], wB.z, tacc[i].z);
                    tacc[i].w = fmaf(xB[i], wB.w, tacc[i].w);
                }
            }
            float4 bv = *(const float4*)(b256 + mt * 64 + tc2);
#pragma unroll
            for (int i = 0; i < 4; ++i) {
                int n = ntile + tr * 4 + i;
                if (n < N_NODES) {
                    float4 y;
                    y.x = tacc[i].x + bv.x; y.y = tacc[i].y + bv.y;
                    y.z = tacc[i].z + bv.z; y.w = tacc[i].w + bv.w;
                    *(float4*)(buf1 + (size_t)n * 256 + mt * 64 + tc2) = y;
                }
            }
        }
    }
}

// ---------------- pooling: segmented, atomic-free, multi-block per graph ----------------
__global__ void k_bounds(const int* __restrict__ gid, int* __restrict__ start) {
    int n = blockIdx.x * 256 + threadIdx.x;
    if (n < N_NODES) {
        int g = gid[n];
        if (n == 0) {
            for (int x = 0; x <= g; ++x) start[x] = 0;
        } else {
            int pg = gid[n - 1];
            for (int x = pg + 1; x <= g; ++x) start[x] = n;
        }
        if (n == N_NODES - 1) {
            for (int x = g + 1; x <= NGRAPH; ++x) start[x] = N_NODES;
        }
    }
}

__global__ void k_gate2(const float* __restrict__ H, const float* __restrict__ H0,
                        const float* __restrict__ gW, const float* __restrict__ gb,
                        float* __restrict__ gate) {
    int l = threadIdx.x & 63;
    int n = blockIdx.x * 4 + (threadIdx.x >> 6);
    float v = H[(size_t)n * 64 + l] * gW[l] + H0[(size_t)n * 64 + l] * gW[64 + l];
    for (int off = 32; off > 0; off >>= 1) v += __shfl_xor(v, off, 64);
    if (l == 0) gate[n] = v + gb[0];
}

__global__ __launch_bounds__(64) void k_poolA(const float* __restrict__ gate,
                                              const int* __restrict__ start,
                                              float* __restrict__ pmax) {
    int g = blockIdx.x, s = blockIdx.y;
    int beg = start[g], len = start[g + 1] - beg;
    int sb = beg + (int)((long long)len * s / PS);
    int se = beg + (int)((long long)len * (s + 1) / PS);
    float m = -INFINITY;
    for (int n = sb + threadIdx.x; n < se; n += 64) m = fmaxf(m, gate[n]);
    for (int off = 32; off > 0; off >>= 1) m = fmaxf(m, __shfl_xor(m, off, 64));
    if (threadIdx.x == 0) pmax[g * PS + s] = m;
}

__global__ void k_poolB(const float* __restrict__ pmax, float* __restrict__ gm) {
    int g = threadIdx.x;  // 64 threads
    float m = -INFINITY;
    for (int s = 0; s < PS; ++s) m = fmaxf(m, pmax[g * PS + s]);
    if (!isfinite(m)) m = 0.0f;   // reference's empty-graph guard
    gm[g] = m;
}

__global__ __launch_bounds__(256) void k_poolC(const float* __restrict__ H,
                                               const float* __restrict__ H0,
                                               const float* __restrict__ gate,
                                               const int* __restrict__ start,
                                               const float* __restrict__ gm,
                                               float* __restrict__ pnum,
                                               float* __restrict__ pden) {
    int g = blockIdx.x, s = blockIdx.y;
    int beg = start[g], len = start[g + 1] - beg;
    int sb = beg + (int)((long long)len * s / PS);
    int se = beg + (int)((long long)len * (s + 1) / PS);
    int t = threadIdx.x;
    int lane = t & 63, wave = t >> 6;
    float m = gm[g];
    __shared__ float shh[4][64], sh0[4][64], ses[4];
    float ah = 0.f, ah0 = 0.f, es = 0.f;
    for (int n = sb + wave; n < se; n += 4) {
        float e = expf(gate[n] - m);
        es += e;
        ah  += e * H [(size_t)n * 64 + lane];
        ah0 += e * H0[(size_t)n * 64 + lane];
    }
    shh[wave][lane] = ah; sh0[wave][lane] = ah0;
    if (lane == 0) ses[wave] = es;
    __syncthreads();
    if (wave == 0) {
        float r  = shh[0][lane] + shh[1][lane] + shh[2][lane] + shh[3][lane];
        float r0 = sh0[0][lane] + sh0[1][lane] + sh0[2][lane] + sh0[3][lane];
        int base = (g * PS + s) * 128;
        pnum[base + lane]      = r;
        pnum[base + 64 + lane] = r0;
        if (lane == 0) pden[g * PS + s] = ses[0] + ses[1] + ses[2] + ses[3];
    }
}

__global__ __launch_bounds__(128) void k_poolD(const float* __restrict__ pnum,
                                               const float* __restrict__ pden,
                                               float* __restrict__ ro) {
    int g = blockIdx.x;
    int c = threadIdx.x;
    float den = 0.f;
    for (int s = 0; s < PS; ++s) den += pden[g * PS + s];
    float nu = 0.f;
    for (int s = 0; s < PS; ++s) nu += pnum[(g * PS + s) * 128 + c];
    ro[g * 128 + c] = (den > 0.f) ? nu / den : 0.f;
}

__global__ void k_logits(const float* __restrict__ ro, const float* __restrict__ oW,
                         const float* __restrict__ ob, float* __restrict__ out) {
    int t = threadIdx.x;
    int b = t >> 1;
    int c = t & 1;
    float acc = ob[c];
    for (int k = 0; k < 128; ++k) acc = fmaf(ro[b * 128 + k], oW[k * 2 + c], acc);
    out[b * 2 + c] = acc;
}

extern "C" void kernel_launch(void* const* d_in, const int* in_sizes, int n_in,
                              void* d_out, int out_size, void* d_ws, size_t ws_size,
                              hipStream_t stream) {
    (void)in_sizes; (void)n_in; (void)out_size; (void)ws_size;
    const float* ann = (const float*)d_in[0];
    const int* src   = (const int*)d_in[1];
    const int* dst   = (const int*)d_in[2];
    const int* ety   = (const int*)d_in[3];
    const int* gid   = (const int*)d_in[4];
    const float* rW  = (const float*)d_in[5];
    const float* rb  = (const float*)d_in[6];
    const float* eW  = (const float*)d_in[7];
    const float* eb  = (const float*)d_in[8];
    const float* Wi  = (const float*)d_in[9];
    const float* Bi  = (const float*)d_in[10];
    const float* Wh  = (const float*)d_in[11];
    const float* Bh  = (const float*)d_in[12];
    const float* gW  = (const float*)d_in[13];
    const float* gb  = (const float*)d_in[14];
    const float* oW  = (const float*)d_in[15];
    const float* ob  = (const float*)d_in[16];
    float* out = (float*)d_out;

    char* p = (char*)d_ws;
    auto take = [&](size_t nbytes) -> void* {
        void* r = (void*)p;
        p += (nbytes + 255) & ~((size_t)255);
        return r;
    };
    float* h0      = (float*)take((size_t)N_NODES * 64 * 4);
    float* h       = (float*)take((size_t)N_NODES * 64 * 4);
    float* abuf    = (float*)take((size_t)N_NODES * 64 * 4);
    float* buf1    = (float*)take((size_t)N_NODES * 256 * 4);   // trans only [N][4*64]
    float* W256    = (float*)take(64 * 256 * 4);
    float* b256    = (float*)take(256 * 4);
    float* Wh192   = (float*)take(64 * 192 * 4);
    float* bh192   = (float*)take(192 * 4);
    float* WiA     = (float*)take(64 * 192 * 4);
    float* biA     = (float*)take(192 * 4);
    int* deg       = (int*)take((size_t)N_NODES * 4);
    int* cur       = (int*)take((size_t)N_NODES * 4);
    int* rs        = (int*)take((size_t)(N_NODES + 1) * 4);
    int* part      = (int*)take(512);
    int* colidx    = (int*)take((size_t)N_EDGES * 4);
    float* gate    = (float*)take((size_t)N_NODES * 4);
    int* start     = (int*)take((size_t)(NGRAPH + 1) * 4);
    float* pmax    = (float*)take(NGRAPH * PS * 4);
    float* gm      = (float*)take(NGRAPH * 4);
    float* pnum    = (float*)take((size_t)NGRAPH * PS * 128 * 4);
    float* pden    = (float*)take(NGRAPH * PS * 4);
    float* ro      = (float*)take(NGRAPH * 128 * 4);

    // ---- CSR build (by dst)
    hipMemsetAsync(deg, 0, (size_t)N_NODES * 4, stream);
    hipMemsetAsync(cur, 0, (size_t)N_NODES * 4, stream);
    k_count<<<(N_EDGES + 255) / 256, 256, 0, stream>>>(dst, deg);
    int nb = (N_NODES + 1023) / 1024;  // 98
    k_scan1<<<nb, 256, 0, stream>>>(deg, rs, part);
    k_scan2<<<1, 64, 0, stream>>>(part, rs, nb);
    k_scan3<<<(N_NODES + 255) / 256, 256, 0, stream>>>(rs, part);
    k_fill<<<(N_EDGES + 255) / 256, 256, 0, stream>>>(src, dst, ety, rs, cur, colidx);

    // ---- weight prep + graph bounds
    k_prep2<<<112, 256, 0, stream>>>(Wh, Bh, eW, eb, Wi, Bi, W256, b256, Wh192, bh192, WiA, biA);
    k_bounds<<<(N_NODES + 255) / 256, 256, 0, stream>>>(gid, start);

    int ntiles = (N_NODES + 127) / 128;  // 782
    int ntiles64 = (N_NODES + 63) / 64;  // 1563

    // ---- reduce layer: h = h0 = ann @ rW + rb (K-pipelined, 64-node tiles)
    k_gemm_red<<<ntiles64, 256, 0, stream>>>(ann, rW, rb, h, h0);

    // ---- pre-loop trans of h0 into buf1
    k_gemm<<<dim3(4, ntiles), 256, 0, stream>>>(h, 64, 64, W256, 256, b256,
                                                buf1, nullptr, 256);

    // ---- message-passing steps: aggregate (R4 form) + fused GRU/trans
    for (int s = 0; s < NSTEPS; ++s) {
        k_aggregate<<<N_NODES / 4, 256, 0, stream>>>(buf1, rs, colidx, abuf);
        k_gruF3<<<ntiles64, 256, 0, stream>>>(abuf, WiA, biA, Wh192, bh192,
                                              W256, b256, h, buf1,
                                              (s < NSTEPS - 1) ? 1 : 0);
    }

    // ---- pooling + classifier (atomic-free, multi-block)
    k_gate2<<<N_NODES / 4, 256, 0, stream>>>(h, h0, gW, gb, gate);
    k_poolA<<<dim3(NGRAPH, PS), 64, 0, stream>>>(gate, start, pmax);
    k_poolB<<<1, 64, 0, stream>>>(pmax, gm);
    k_poolC<<<dim3(NGRAPH, PS), 256, 0, stream>>>(h, h0, gate, start, gm, pnum, pden);
    k_poolD<<<NGRAPH, 128, 0, stream>>>(pnum, pden, ro);
    k_logits<<<1, 128, 0, stream>>>(ro, oW, ob, out);
}

// Round 11
// 1546.057 us; speedup vs baseline: 1.1715x; 1.0019x over previous
//
#include <hip/hip_runtime.h>
#include <cstdint>
#include <cstddef>

#define N_NODES 100000
#define N_EDGES 1200000
#define ASIZE 256
#define HSIZE 64
#define NTYPES 4
#define NSTEPS 6
#define NGRAPH 64
#define PS 16   // pooling splits per graph

static __device__ __forceinline__ float sigmoidf_(float x) { return 1.0f / (1.0f + expf(-x)); }

// ---------------- CSR build (by dst) ----------------
__global__ void k_count(const int* __restrict__ dst, int* __restrict__ deg) {
    int e = blockIdx.x * 256 + threadIdx.x;
    if (e < N_EDGES) atomicAdd(&deg[dst[e]], 1);
}

__global__ void k_scan1(const int* __restrict__ deg, int* __restrict__ rs, int* __restrict__ part) {
    __shared__ int sh[256];
    int t = threadIdx.x;
    int base = blockIdx.x * 1024 + t * 4;
    int v0 = (base + 0 < N_NODES) ? deg[base + 0] : 0;
    int v1 = (base + 1 < N_NODES) ? deg[base + 1] : 0;
    int v2 = (base + 2 < N_NODES) ? deg[base + 2] : 0;
    int v3 = (base + 3 < N_NODES) ? deg[base + 3] : 0;
    int s = v0 + v1 + v2 + v3;
    sh[t] = s;
    __syncthreads();
    for (int off = 1; off < 256; off <<= 1) {
        int x = (t >= off) ? sh[t - off] : 0;
        __syncthreads();
        sh[t] += x;
        __syncthreads();
    }
    int excl = sh[t] - s;
    if (t == 255) part[blockIdx.x] = sh[255];
    if (base + 0 < N_NODES) rs[base + 0] = excl;
    if (base + 1 < N_NODES) rs[base + 1] = excl + v0;
    if (base + 2 < N_NODES) rs[base + 2] = excl + v0 + v1;
    if (base + 3 < N_NODES) rs[base + 3] = excl + v0 + v1 + v2;
}

__global__ void k_scan2(int* __restrict__ part, int* __restrict__ rs, int nb) {
    if (threadIdx.x == 0 && blockIdx.x == 0) {
        int run = 0;
        for (int i = 0; i < nb; ++i) { int v = part[i]; part[i] = run; run += v; }
        rs[N_NODES] = run;
    }
}

__global__ void k_scan3(int* __restrict__ rs, const int* __restrict__ part) {
    int i = blockIdx.x * 256 + threadIdx.x;
    if (i < N_NODES) rs[i] += part[i >> 10];
}

// colidx holds a precomputed float-offset into buf1 ([N][256] trans-only): src*256 + ety*64
__global__ void k_fill(const int* __restrict__ src, const int* __restrict__ dst,
                       const int* __restrict__ ety, const int* __restrict__ rs,
                       int* __restrict__ cur, int* __restrict__ colidx) {
    int e = blockIdx.x * 256 + threadIdx.x;
    if (e < N_EDGES) {
        int d = dst[e];
        int pos = rs[d] + atomicAdd(&cur[d], 1);
        colidx[pos] = src[e] * 256 + ety[e] * 64;
    }
}

// ---------------- weight prep ----------------
__global__ void k_prep2(const float* __restrict__ Wh, const float* __restrict__ Bh,
                        const float* __restrict__ eW, const float* __restrict__ eb,
                        const float* __restrict__ Wi, const float* __restrict__ Bi,
                        float* __restrict__ W256, float* __restrict__ b256,
                        float* __restrict__ Wh192, float* __restrict__ bh192,
                        float* __restrict__ WiA, float* __restrict__ biA) {
    int idx = blockIdx.x * 256 + threadIdx.x;
    if (idx < 64 * 256) {
        int k = idx / 256, c = idx % 256;
        W256[idx] = eW[(size_t)(c >> 6) * 4096 + k * 64 + (c & 63)];
    }
    if (idx < 64 * 192) {
        int k = idx / 192, m = idx % 192;
        int j = m / 3, g = m % 3;
        WiA[idx]   = Wi[(g * 64 + j) * 64 + k];
        Wh192[idx] = Wh[(g * 64 + j) * 64 + k];
    }
    if (idx < 256) b256[idx] = eb[idx];
    if (idx < 192) {
        biA[idx]   = Bi[(idx % 3) * 64 + idx / 3];
        bh192[idx] = Bh[(idx % 3) * 64 + idx / 3];
    }
}

// ---------------- generic tiled GEMM (used once: pre-loop trans of h0) ----------------
__global__ __launch_bounds__(256) void k_gemm(const float* __restrict__ X, int ldx, int K,
                                              const float* __restrict__ W, int ldw,
                                              const float* __restrict__ bias,
                                              float* __restrict__ Y, float* __restrict__ Y2,
                                              int M) {
    __shared__ float sX[128 * 66];
    __shared__ float sW[64 * 64];
    int tid = threadIdx.x;
    int mtile = blockIdx.x * 64;
    int ntile = blockIdx.y * 128;
    int tc4 = (tid & 15) * 4;
    int tr = tid >> 4;
    float4 acc[8];
#pragma unroll
    for (int i = 0; i < 8; ++i) acc[i] = make_float4(0.f, 0.f, 0.f, 0.f);

    int nkc = K >> 6;
    for (int kc = 0; kc < nkc; ++kc) {
        if (kc) __syncthreads();
#pragma unroll
        for (int i = 0; i < 8; ++i) {
            int lin4 = (i * 256 + tid) * 4;
            int nl = lin4 >> 6, kk = lin4 & 63;
            int n = ntile + nl;
            float4 v = make_float4(0.f, 0.f, 0.f, 0.f);
            if (n < N_NODES) v = *(const float4*)(X + (size_t)n * ldx + kc * 64 + kk);
            float* d = sX + nl * 66 + kk;
            d[0] = v.x; d[1] = v.y; d[2] = v.z; d[3] = v.w;
        }
#pragma unroll
        for (int i = 0; i < 4; ++i) {
            int lin4 = (i * 256 + tid) * 4;
            int kk = lin4 >> 6, c = lin4 & 63;
            float4 v = *(const float4*)(W + (size_t)(kc * 64 + kk) * ldw + mtile + c);
            *(float4*)(sW + kk * 64 + c) = v;
        }
        __syncthreads();
        const float* xr = sX + tr * 8 * 66;
        const float* wr = sW + tc4;
        for (int kk = 0; kk < 64; kk += 2) {
            float4 wA = *(const float4*)(wr + kk * 64);
            float4 wB = *(const float4*)(wr + (kk + 1) * 64);
            float xA[8], xB[8];
#pragma unroll
            for (int i = 0; i < 8; ++i) { xA[i] = xr[i * 66 + kk]; xB[i] = xr[i * 66 + kk + 1]; }
#pragma unroll
            for (int i = 0; i < 8; ++i) {
                acc[i].x = fmaf(xA[i], wA.x, acc[i].x);
                acc[i].y = fmaf(xA[i], wA.y, acc[i].y);
                acc[i].z = fmaf(xA[i], wA.z, acc[i].z);
                acc[i].w = fmaf(xA[i], wA.w, acc[i].w);
            }
#pragma unroll
            for (int i = 0; i < 8; ++i) {
                acc[i].x = fmaf(xB[i], wB.x, acc[i].x);
                acc[i].y = fmaf(xB[i], wB.y, acc[i].y);
                acc[i].z = fmaf(xB[i], wB.z, acc[i].z);
                acc[i].w = fmaf(xB[i], wB.w, acc[i].w);
            }
        }
    }
    float4 bv = *(const float4*)(bias + mtile + tc4);
#pragma unroll
    for (int i = 0; i < 8; ++i) {
        int n = ntile + tr * 8 + i;
        if (n < N_NODES) {
            float4 y;
            y.x = acc[i].x + bv.x; y.y = acc[i].y + bv.y;
            y.z = acc[i].z + bv.z; y.w = acc[i].w + bv.w;
            *(float4*)(Y + (size_t)n * M + mtile + tc4) = y;
            if (Y2) *(float4*)(Y2 + (size_t)n * M + mtile + tc4) = y;
        }
    }
}

// ---------------- reduce GEMM: h = h0 = ann[N][256] @ rW[256][64] + rb (K-pipelined) -------
__global__ __launch_bounds__(256) void k_gemm_red(const float* __restrict__ X,
                                                  const float* __restrict__ W,
                                                  const float* __restrict__ bias,
                                                  float* __restrict__ Y,
                                                  float* __restrict__ Y2) {
    __shared__ float sX[128 * 66];
    __shared__ float sW[64 * 64];
    int tid = threadIdx.x;
    int ntile = blockIdx.x * 128;
    int tc4 = (tid & 15) * 4;
    int tr = tid >> 4;
    int swr = tid >> 4;
    int swc = (tid & 15) * 4;

    float4 acc[8];
#pragma unroll
    for (int i = 0; i < 8; ++i) acc[i] = make_float4(0.f, 0.f, 0.f, 0.f);

    float4 xreg[8];
    float4 wreg[4];
#pragma unroll
    for (int i = 0; i < 8; ++i) {
        int lin4 = (i * 256 + tid) * 4;
        int nl = lin4 >> 6, kk = lin4 & 63;
        int n = ntile + nl;
        float4 v = make_float4(0.f, 0.f, 0.f, 0.f);
        if (n < N_NODES) v = *(const float4*)(X + (size_t)n * 256 + kk);
        xreg[i] = v;
    }
#pragma unroll
    for (int i = 0; i < 4; ++i)
        wreg[i] = *(const float4*)(W + (size_t)(i * 16 + swr) * 64 + swc);

    for (int kc = 0; kc < 4; ++kc) {
#pragma unroll
        for (int i = 0; i < 8; ++i) {
            int lin4 = (i * 256 + tid) * 4;
            int nl = lin4 >> 6, kk = lin4 & 63;
            float* d = sX + nl * 66 + kk;
            d[0] = xreg[i].x; d[1] = xreg[i].y; d[2] = xreg[i].z; d[3] = xreg[i].w;
        }
#pragma unroll
        for (int i = 0; i < 4; ++i)
            *(float4*)(sW + (i * 16 + swr) * 64 + swc) = wreg[i];
        __syncthreads();
        if (kc < 3) {
#pragma unroll
            for (int i = 0; i < 8; ++i) {
                int lin4 = (i * 256 + tid) * 4;
                int nl = lin4 >> 6, kk = lin4 & 63;
                int n = ntile + nl;
                float4 v = make_float4(0.f, 0.f, 0.f, 0.f);
                if (n < N_NODES) v = *(const float4*)(X + (size_t)n * 256 + (kc + 1) * 64 + kk);
                xreg[i] = v;
            }
#pragma unroll
            for (int i = 0; i < 4; ++i)
                wreg[i] = *(const float4*)(W + (size_t)((kc + 1) * 64 + i * 16 + swr) * 64 + swc);
        }
        const float* xr = sX + tr * 8 * 66;
        const float* wrp = sW + tc4;
        for (int kk = 0; kk < 64; kk += 2) {
            float4 wA = *(const float4*)(wrp + kk * 64);
            float4 wB = *(const float4*)(wrp + (kk + 1) * 64);
            float xA[8], xB[8];
#pragma unroll
            for (int i = 0; i < 8; ++i) { xA[i] = xr[i * 66 + kk]; xB[i] = xr[i * 66 + kk + 1]; }
#pragma unroll
            for (int i = 0; i < 8; ++i) {
                acc[i].x = fmaf(xA[i], wA.x, acc[i].x);
                acc[i].y = fmaf(xA[i], wA.y, acc[i].y);
                acc[i].z = fmaf(xA[i], wA.z, acc[i].z);
                acc[i].w = fmaf(xA[i], wA.w, acc[i].w);
            }
#pragma unroll
            for (int i = 0; i < 8; ++i) {
                acc[i].x = fmaf(xB[i], wB.x, acc[i].x);
                acc[i].y = fmaf(xB[i], wB.y, acc[i].y);
                acc[i].z = fmaf(xB[i], wB.z, acc[i].z);
                acc[i].w = fmaf(xB[i], wB.w, acc[i].w);
            }
        }
        if (kc < 3) __syncthreads();
    }
    float4 bv = *(const float4*)(bias + tc4);
#pragma unroll
    for (int i = 0; i < 8; ++i) {
        int n = ntile + tr * 8 + i;
        if (n < N_NODES) {
            float4 y;
            y.x = acc[i].x + bv.x; y.y = acc[i].y + bv.y;
            y.z = acc[i].z + bv.z; y.w = acc[i].w + bv.w;
            *(float4*)(Y + (size_t)n * 64 + tc4) = y;
            *(float4*)(Y2 + (size_t)n * 64 + tc4) = y;
        }
    }
}

// ---------------- edge aggregate: a[n] = sum of incoming trans rows from buf1 ----------------
// R4 form — proven best across both brackets (R8: more ILP/fewer waves worse; R7: in-GEMM
// worse). 1 node/wave, 16 lanes/edge x float4, masked 7-slot final batch, max occupancy.
__global__ void k_aggregate(const float* __restrict__ buf1, const int* __restrict__ rs,
                            const int* __restrict__ colidx, float* __restrict__ a) {
    int l = threadIdx.x & 63;
    int n = blockIdx.x * 4 + (threadIdx.x >> 6);  // 25000 blocks * 4 = N exactly
    int sub = l >> 4;            // edge slot within group of 4
    int kq = (l & 15) * 4;       // k quad handled by this lane
    int beg = rs[n], end = rs[n + 1];             // wave-uniform
    int deg = end - beg;
    int c4end = beg + (deg & ~3);                 // end of 4-aligned main portion
    float4 acc = make_float4(0.f, 0.f, 0.f, 0.f);
    int s = beg;
    for (; s + 31 < c4end; s += 32) {
        int c0 = colidx[s + sub];
        int c1 = colidx[s + 4 + sub];
        int c2 = colidx[s + 8 + sub];
        int c3 = colidx[s + 12 + sub];
        int c4 = colidx[s + 16 + sub];
        int c5 = colidx[s + 20 + sub];
        int c6 = colidx[s + 24 + sub];
        int c7 = colidx[s + 28 + sub];
        float4 v0 = *(const float4*)(buf1 + (size_t)c0 + kq);
        float4 v1 = *(const float4*)(buf1 + (size_t)c1 + kq);
        float4 v2 = *(const float4*)(buf1 + (size_t)c2 + kq);
        float4 v3 = *(const float4*)(buf1 + (size_t)c3 + kq);
        float4 v4 = *(const float4*)(buf1 + (size_t)c4 + kq);
        float4 v5 = *(const float4*)(buf1 + (size_t)c5 + kq);
        float4 v6 = *(const float4*)(buf1 + (size_t)c6 + kq);
        float4 v7 = *(const float4*)(buf1 + (size_t)c7 + kq);
        acc.x += v0.x; acc.y += v0.y; acc.z += v0.z; acc.w += v0.w;
        acc.x += v1.x; acc.y += v1.y; acc.z += v1.z; acc.w += v1.w;
        acc.x += v2.x; acc.y += v2.y; acc.z += v2.z; acc.w += v2.w;
        acc.x += v3.x; acc.y += v3.y; acc.z += v3.z; acc.w += v3.w;
        acc.x += v4.x; acc.y += v4.y; acc.z += v4.z; acc.w += v4.w;
        acc.x += v5.x; acc.y += v5.y; acc.z += v5.z; acc.w += v5.w;
        acc.x += v6.x; acc.y += v6.y; acc.z += v6.z; acc.w += v6.w;
        acc.x += v7.x; acc.y += v7.y; acc.z += v7.z; acc.w += v7.w;
    }
    {
        int nv = (c4end - s) >> 2;
        float4 vv[7];
#pragma unroll
        for (int k = 0; k < 7; ++k) {
            if (k < nv) {
                int c = colidx[s + k * 4 + sub];
                vv[k] = *(const float4*)(buf1 + (size_t)c + kq);
            }
        }
#pragma unroll
        for (int k = 0; k < 7; ++k) {
            if (k < nv) {
                acc.x += vv[k].x; acc.y += vv[k].y; acc.z += vv[k].z; acc.w += vv[k].w;
            }
        }
        s += nv * 4;
    }
    for (; s < end; ++s) {
        if (sub == 0) {
            int c = colidx[s];
            float4 v = *(const float4*)(buf1 + (size_t)c + kq);
            acc.x += v.x; acc.y += v.y; acc.z += v.z; acc.w += v.w;
        }
    }
    float4 t;
    t.x = acc.x + __shfl_xor(acc.x, 16, 64);
    t.y = acc.y + __shfl_xor(acc.y, 16, 64);
    t.z = acc.z + __shfl_xor(acc.z, 16, 64);
    t.w = acc.w + __shfl_xor(acc.w, 16, 64);
    float4 r;
    r.x = t.x + __shfl_xor(t.x, 32, 64);
    r.y = t.y + __shfl_xor(t.y, 32, 64);
    r.z = t.z + __shfl_xor(t.z, 32, 64);
    r.w = t.w + __shfl_xor(t.w, 32, 64);
    if (sub == 0) *(float4*)(a + (size_t)n * 64 + kq) = r;
}

// ---------------- fused: gi-GEMM + gh-GEMM + GRU + trans-GEMM for next step ----------------
// R4 k_gruF3 — proven best (143-147us): sW staged in LDS, transposed-X b128 reads, trans
// tail writes buf1 for the next step's aggregate.
__global__ __launch_bounds__(256) void k_gruF3(const float* __restrict__ A,
                                               const float* __restrict__ WiA,
                                               const float* __restrict__ biA,
                                               const float* __restrict__ Wh192,
                                               const float* __restrict__ bh192,
                                               const float* __restrict__ W256,
                                               const float* __restrict__ b256,
                                               float* __restrict__ H,
                                               float* __restrict__ buf1,
                                               int do_trans) {
    __shared__ float sXT[32 * 68];   // [k][node], stride 68 (16B-aligned rows)
    __shared__ float sW[32 * 192];   // gi/gh W chunks; reused as [64][64] for trans chunks
    __shared__ float sHT[64 * 68];   // h_new transposed [k][node]
    int tid = threadIdx.x;
    int ntile = blockIdx.x * 64;
    int tc = tid & 15;
    int tr = tid >> 4;
    float acc[2][4][12];
#pragma unroll
    for (int p = 0; p < 2; ++p)
#pragma unroll
        for (int i = 0; i < 4; ++i)
#pragma unroll
            for (int c = 0; c < 12; ++c) acc[p][i][c] = 0.f;

#pragma unroll
    for (int ph = 0; ph < 2; ++ph) {
        const float* Xsrc = (ph == 0) ? A : H;
        const float* Wsrc = (ph == 0) ? WiA : Wh192;
        for (int kc = 0; kc < 2; ++kc) {
            if (ph || kc) __syncthreads();
            // stage X transposed: 64 nodes x 32 k
#pragma unroll
            for (int i = 0; i < 2; ++i) {
                int lin = i * 256 + tid;             // 0..511 float4s
                int nl = lin >> 3;                   // node 0..63
                int kk = (lin & 7) * 4;              // k 0..28
                int n = ntile + nl;
                float4 v = make_float4(0.f, 0.f, 0.f, 0.f);
                if (n < N_NODES) v = *(const float4*)(Xsrc + (size_t)n * 64 + kc * 32 + kk);
                sXT[(kk + 0) * 68 + nl] = v.x;
                sXT[(kk + 1) * 68 + nl] = v.y;
                sXT[(kk + 2) * 68 + nl] = v.z;
                sXT[(kk + 3) * 68 + nl] = v.w;
            }
            {
                int kk = tid >> 3, c = (tid & 7) * 24;
                const float* srcp = Wsrc + (size_t)(kc * 32 + kk) * 192 + c;
                float* d = sW + kk * 192 + c;
#pragma unroll
                for (int u = 0; u < 6; ++u) *(float4*)(d + 4 * u) = *(const float4*)(srcp + 4 * u);
            }
            __syncthreads();
            const float* wr = sW + tc * 12;
            for (int kk = 0; kk < 32; kk += 2) {
                float4 w0 = *(const float4*)(wr + kk * 192);
                float4 w1 = *(const float4*)(wr + kk * 192 + 4);
                float4 w2 = *(const float4*)(wr + kk * 192 + 8);
                float4 u0 = *(const float4*)(wr + (kk + 1) * 192);
                float4 u1 = *(const float4*)(wr + (kk + 1) * 192 + 4);
                float4 u2 = *(const float4*)(wr + (kk + 1) * 192 + 8);
                float4 xA4 = *(const float4*)(sXT + kk * 68 + tr * 4);
                float4 xB4 = *(const float4*)(sXT + (kk + 1) * 68 + tr * 4);
                float xA[4] = {xA4.x, xA4.y, xA4.z, xA4.w};
                float xB[4] = {xB4.x, xB4.y, xB4.z, xB4.w};
#pragma unroll
                for (int i = 0; i < 4; ++i) {
                    acc[ph][i][0]  = fmaf(xA[i], w0.x, acc[ph][i][0]);
                    acc[ph][i][1]  = fmaf(xA[i], w0.y, acc[ph][i][1]);
                    acc[ph][i][2]  = fmaf(xA[i], w0.z, acc[ph][i][2]);
                    acc[ph][i][3]  = fmaf(xA[i], w0.w, acc[ph][i][3]);
                    acc[ph][i][4]  = fmaf(xA[i], w1.x, acc[ph][i][4]);
                    acc[ph][i][5]  = fmaf(xA[i], w1.y, acc[ph][i][5]);
                    acc[ph][i][6]  = fmaf(xA[i], w1.z, acc[ph][i][6]);
                    acc[ph][i][7]  = fmaf(xA[i], w1.w, acc[ph][i][7]);
                    acc[ph][i][8]  = fmaf(xA[i], w2.x, acc[ph][i][8]);
                    acc[ph][i][9]  = fmaf(xA[i], w2.y, acc[ph][i][9]);
                    acc[ph][i][10] = fmaf(xA[i], w2.z, acc[ph][i][10]);
                    acc[ph][i][11] = fmaf(xA[i], w2.w, acc[ph][i][11]);
                }
#pragma unroll
                for (int i = 0; i < 4; ++i) {
                    acc[ph][i][0]  = fmaf(xB[i], u0.x, acc[ph][i][0]);
                    acc[ph][i][1]  = fmaf(xB[i], u0.y, acc[ph][i][1]);
                    acc[ph][i][2]  = fmaf(xB[i], u0.z, acc[ph][i][2]);
                    acc[ph][i][3]  = fmaf(xB[i], u0.w, acc[ph][i][3]);
                    acc[ph][i][4]  = fmaf(xB[i], u1.x, acc[ph][i][4]);
                    acc[ph][i][5]  = fmaf(xB[i], u1.y, acc[ph][i][5]);
                    acc[ph][i][6]  = fmaf(xB[i], u1.z, acc[ph][i][6]);
                    acc[ph][i][7]  = fmaf(xB[i], u1.w, acc[ph][i][7]);
                    acc[ph][i][8]  = fmaf(xB[i], u2.x, acc[ph][i][8]);
                    acc[ph][i][9]  = fmaf(xB[i], u2.y, acc[ph][i][9]);
                    acc[ph][i][10] = fmaf(xB[i], u2.z, acc[ph][i][10]);
                    acc[ph][i][11] = fmaf(xB[i], u2.w, acc[ph][i][11]);
                }
            }
        }
    }
    // epilogue: GRU gates; write h_new to global H and (transposed) to sHT
    float bb[12], bh[12];
    {
        float4 b0 = *(const float4*)(biA + tc * 12);
        float4 b1 = *(const float4*)(biA + tc * 12 + 4);
        float4 b2 = *(const float4*)(biA + tc * 12 + 8);
        bb[0] = b0.x; bb[1] = b0.y; bb[2] = b0.z; bb[3] = b0.w;
        bb[4] = b1.x; bb[5] = b1.y; bb[6] = b1.z; bb[7] = b1.w;
        bb[8] = b2.x; bb[9] = b2.y; bb[10] = b2.z; bb[11] = b2.w;
        float4 c0 = *(const float4*)(bh192 + tc * 12);
        float4 c1 = *(const float4*)(bh192 + tc * 12 + 4);
        float4 c2 = *(const float4*)(bh192 + tc * 12 + 8);
        bh[0] = c0.x; bh[1] = c0.y; bh[2] = c0.z; bh[3] = c0.w;
        bh[4] = c1.x; bh[5] = c1.y; bh[6] = c1.z; bh[7] = c1.w;
        bh[8] = c2.x; bh[9] = c2.y; bh[10] = c2.z; bh[11] = c2.w;
    }
#pragma unroll
    for (int i = 0; i < 4; ++i) {
        int n = ntile + tr * 4 + i;
        if (n >= N_NODES) continue;
        float gg[12];
#pragma unroll
        for (int c = 0; c < 12; ++c) gg[c] = acc[1][i][c] + bh[c];
        float4 hv = *(const float4*)(H + (size_t)n * 64 + tc * 4);
        float res[4];
#pragma unroll
        for (int jj = 0; jj < 4; ++jj) {
            int c = jj * 3;
            float r = sigmoidf_(acc[0][i][c] + bb[c] + gg[c]);
            float z = sigmoidf_(acc[0][i][c + 1] + bb[c + 1] + gg[c + 1]);
            float nn = tanhf(acc[0][i][c + 2] + bb[c + 2] + r * gg[c + 2]);
            float hj = (jj == 0) ? hv.x : (jj == 1) ? hv.y : (jj == 2) ? hv.z : hv.w;
            res[jj] = (1.f - z) * nn + z * hj;
        }
        float4 o; o.x = res[0]; o.y = res[1]; o.z = res[2]; o.w = res[3];
        *(float4*)(H + (size_t)n * 64 + tc * 4) = o;
        if (do_trans) {
#pragma unroll
            for (int jj = 0; jj < 4; ++jj)
                sHT[(tc * 4 + jj) * 68 + (tr * 4 + i)] = res[jj];
        }
    }
    // trans tail: buf1 = h_new @ W256 + b256 (4 x 64-col chunks)
    if (do_trans) {
        __syncthreads();   // sHT complete; all phase readers of sW done
        int tc2 = tc * 4;
        for (int mt = 0; mt < 4; ++mt) {
            if (mt) __syncthreads();
#pragma unroll
            for (int i = 0; i < 4; ++i) {
                int idx = i * 256 + tid;            // 0..1023 float4s
                int row = idx >> 4, c4 = (idx & 15) * 4;
                *(float4*)(sW + row * 64 + c4) =
                    *(const float4*)(W256 + (size_t)row * 256 + mt * 64 + c4);
            }
            __syncthreads();
            float4 tacc[4];
#pragma unroll
            for (int i = 0; i < 4; ++i) tacc[i] = make_float4(0.f, 0.f, 0.f, 0.f);
            for (int kk = 0; kk < 64; kk += 2) {
                float4 wA = *(const float4*)(sW + kk * 64 + tc2);
                float4 wB = *(const float4*)(sW + (kk + 1) * 64 + tc2);
                float4 xA4 = *(const float4*)(sHT + kk * 68 + tr * 4);
                float4 xB4 = *(const float4*)(sHT + (kk + 1) * 68 + tr * 4);
                float xA[4] = {xA4.x, xA4.y, xA4.z, xA4.w};
                float xB[4] = {xB4.x, xB4.y, xB4.z, xB4.w};
#pragma unroll
                for (int i = 0; i < 4; ++i) {
                    tacc[i].x = fmaf(xA[i], wA.x, tacc[i].x);
                    tacc[i].y = fmaf(xA[i], wA.y, tacc[i].y);
                    tacc[i].z = fmaf(xA[i], wA.z, tacc[i].z);
                    tacc[i].w = fmaf(xA[i], wA.w, tacc[i].w);
                }
#pragma unroll
                for (int i = 0; i < 4; ++i) {
                    tacc[i].x = fmaf(xB[i], wB.x, tacc[i].x);
                    tacc[i].y = fmaf(xB[i], wB.y, tacc[i].y);
                    tacc[i].z = fmaf(xB[i], wB.z, tacc[i].z);
                    tacc[i].w = fmaf(xB[i], wB.w, tacc[i].w);
                }
            }
            float4 bv = *(const float4*)(b256 + mt * 64 + tc2);
#pragma unroll
            for (int i = 0; i < 4; ++i) {
                int n = ntile + tr * 4 + i;
                if (n < N_NODES) {
                    float4 y;
                    y.x = tacc[i].x + bv.x; y.y = tacc[i].y + bv.y;
                    y.z = tacc[i].z + bv.z; y.w = tacc[i].w + bv.w;
                    *(float4*)(buf1 + (size_t)n * 256 + mt * 64 + tc2) = y;
                }
            }
        }
    }
}

// ---------------- pooling: segmented, atomic-free, multi-block per graph ----------------
__global__ void k_bounds(const int* __restrict__ gid, int* __restrict__ start) {
    int n = blockIdx.x * 256 + threadIdx.x;
    if (n < N_NODES) {
        int g = gid[n];
        if (n == 0) {
            for (int x = 0; x <= g; ++x) start[x] = 0;
        } else {
            int pg = gid[n - 1];
            for (int x = pg + 1; x <= g; ++x) start[x] = n;
        }
        if (n == N_NODES - 1) {
            for (int x = g + 1; x <= NGRAPH; ++x) start[x] = N_NODES;
        }
    }
}

__global__ void k_gate2(const float* __restrict__ H, const float* __restrict__ H0,
                        const float* __restrict__ gW, const float* __restrict__ gb,
                        float* __restrict__ gate) {
    int l = threadIdx.x & 63;
    int n = blockIdx.x * 4 + (threadIdx.x >> 6);
    float v = H[(size_t)n * 64 + l] * gW[l] + H0[(size_t)n * 64 + l] * gW[64 + l];
    for (int off = 32; off > 0; off >>= 1) v += __shfl_xor(v, off, 64);
    if (l == 0) gate[n] = v + gb[0];
}

__global__ __launch_bounds__(64) void k_poolA(const float* __restrict__ gate,
                                              const int* __restrict__ start,
                                              float* __restrict__ pmax) {
    int g = blockIdx.x, s = blockIdx.y;
    int beg = start[g], len = start[g + 1] - beg;
    int sb = beg + (int)((long long)len * s / PS);
    int se = beg + (int)((long long)len * (s + 1) / PS);
    float m = -INFINITY;
    for (int n = sb + threadIdx.x; n < se; n += 64) m = fmaxf(m, gate[n]);
    for (int off = 32; off > 0; off >>= 1) m = fmaxf(m, __shfl_xor(m, off, 64));
    if (threadIdx.x == 0) pmax[g * PS + s] = m;
}

__global__ void k_poolB(const float* __restrict__ pmax, float* __restrict__ gm) {
    int g = threadIdx.x;  // 64 threads
    float m = -INFINITY;
    for (int s = 0; s < PS; ++s) m = fmaxf(m, pmax[g * PS + s]);
    if (!isfinite(m)) m = 0.0f;   // reference's empty-graph guard
    gm[g] = m;
}

__global__ __launch_bounds__(256) void k_poolC(const float* __restrict__ H,
                                               const float* __restrict__ H0,
                                               const float* __restrict__ gate,
                                               const int* __restrict__ start,
                                               const float* __restrict__ gm,
                                               float* __restrict__ pnum,
                                               float* __restrict__ pden) {
    int g = blockIdx.x, s = blockIdx.y;
    int beg = start[g], len = start[g + 1] - beg;
    int sb = beg + (int)((long long)len * s / PS);
    int se = beg + (int)((long long)len * (s + 1) / PS);
    int t = threadIdx.x;
    int lane = t & 63, wave = t >> 6;
    float m = gm[g];
    __shared__ float shh[4][64], sh0[4][64], ses[4];
    float ah = 0.f, ah0 = 0.f, es = 0.f;
    for (int n = sb + wave; n < se; n += 4) {
        float e = expf(gate[n] - m);
        es += e;
        ah  += e * H [(size_t)n * 64 + lane];
        ah0 += e * H0[(size_t)n * 64 + lane];
    }
    shh[wave][lane] = ah; sh0[wave][lane] = ah0;
    if (lane == 0) ses[wave] = es;
    __syncthreads();
    if (wave == 0) {
        float r  = shh[0][lane] + shh[1][lane] + shh[2][lane] + shh[3][lane];
        float r0 = sh0[0][lane] + sh0[1][lane] + sh0[2][lane] + sh0[3][lane];
        int base = (g * PS + s) * 128;
        pnum[base + lane]      = r;
        pnum[base + 64 + lane] = r0;
        if (lane == 0) pden[g * PS + s] = ses[0] + ses[1] + ses[2] + ses[3];
    }
}

__global__ __launch_bounds__(128) void k_poolD(const float* __restrict__ pnum,
                                               const float* __restrict__ pden,
                                               float* __restrict__ ro) {
    int g = blockIdx.x;
    int c = threadIdx.x;
    float den = 0.f;
    for (int s = 0; s < PS; ++s) den += pden[g * PS + s];
    float nu = 0.f;
    for (int s = 0; s < PS; ++s) nu += pnum[(g * PS + s) * 128 + c];
    ro[g * 128 + c] = (den > 0.f) ? nu / den : 0.f;
}

__global__ void k_logits(const float* __restrict__ ro, const float* __restrict__ oW,
                         const float* __restrict__ ob, float* __restrict__ out) {
    int t = threadIdx.x;
    int b = t >> 1;
    int c = t & 1;
    float acc = ob[c];
    for (int k = 0; k < 128; ++k) acc = fmaf(ro[b * 128 + k], oW[k * 2 + c], acc);
    out[b * 2 + c] = acc;
}

extern "C" void kernel_launch(void* const* d_in, const int* in_sizes, int n_in,
                              void* d_out, int out_size, void* d_ws, size_t ws_size,
                              hipStream_t stream) {
    (void)in_sizes; (void)n_in; (void)out_size; (void)ws_size;
    const float* ann = (const float*)d_in[0];
    const int* src   = (const int*)d_in[1];
    const int* dst   = (const int*)d_in[2];
    const int* ety   = (const int*)d_in[3];
    const int* gid   = (const int*)d_in[4];
    const float* rW  = (const float*)d_in[5];
    const float* rb  = (const float*)d_in[6];
    const float* eW  = (const float*)d_in[7];
    const float* eb  = (const float*)d_in[8];
    const float* Wi  = (const float*)d_in[9];
    const float* Bi  = (const float*)d_in[10];
    const float* Wh  = (const float*)d_in[11];
    const float* Bh  = (const float*)d_in[12];
    const float* gW  = (const float*)d_in[13];
    const float* gb  = (const float*)d_in[14];
    const float* oW  = (const float*)d_in[15];
    const float* ob  = (const float*)d_in[16];
    float* out = (float*)d_out;

    char* p = (char*)d_ws;
    auto take = [&](size_t nbytes) -> void* {
        void* r = (void*)p;
        p += (nbytes + 255) & ~((size_t)255);
        return r;
    };
    float* h0      = (float*)take((size_t)N_NODES * 64 * 4);
    float* h       = (float*)take((size_t)N_NODES * 64 * 4);
    float* abuf    = (float*)take((size_t)N_NODES * 64 * 4);
    float* buf1    = (float*)take((size_t)N_NODES * 256 * 4);   // trans only [N][4*64]
    float* W256    = (float*)take(64 * 256 * 4);
    float* b256    = (float*)take(256 * 4);
    float* Wh192   = (float*)take(64 * 192 * 4);
    float* bh192   = (float*)take(192 * 4);
    float* WiA     = (float*)take(64 * 192 * 4);
    float* biA     = (float*)take(192 * 4);
    int* deg       = (int*)take((size_t)N_NODES * 4);
    int* cur       = (int*)take((size_t)N_NODES * 4);
    int* rs        = (int*)take((size_t)(N_NODES + 1) * 4);
    int* part      = (int*)take(512);
    int* colidx    = (int*)take((size_t)N_EDGES * 4);
    float* gate    = (float*)take((size_t)N_NODES * 4);
    int* start     = (int*)take((size_t)(NGRAPH + 1) * 4);
    float* pmax    = (float*)take(NGRAPH * PS * 4);
    float* gm      = (float*)take(NGRAPH * 4);
    float* pnum    = (float*)take((size_t)NGRAPH * PS * 128 * 4);
    float* pden    = (float*)take(NGRAPH * PS * 4);
    float* ro      = (float*)take(NGRAPH * 128 * 4);

    // ---- CSR build (by dst)
    hipMemsetAsync(deg, 0, (size_t)N_NODES * 4, stream);
    hipMemsetAsync(cur, 0, (size_t)N_NODES * 4, stream);
    k_count<<<(N_EDGES + 255) / 256, 256, 0, stream>>>(dst, deg);
    int nb = (N_NODES + 1023) / 1024;  // 98
    k_scan1<<<nb, 256, 0, stream>>>(deg, rs, part);
    k_scan2<<<1, 64, 0, stream>>>(part, rs, nb);
    k_scan3<<<(N_NODES + 255) / 256, 256, 0, stream>>>(rs, part);
    k_fill<<<(N_EDGES + 255) / 256, 256, 0, stream>>>(src, dst, ety, rs, cur, colidx);

    // ---- weight prep + graph bounds
    k_prep2<<<112, 256, 0, stream>>>(Wh, Bh, eW, eb, Wi, Bi, W256, b256, Wh192, bh192, WiA, biA);
    k_bounds<<<(N_NODES + 255) / 256, 256, 0, stream>>>(gid, start);

    int ntiles = (N_NODES + 127) / 128;  // 782

    // ---- reduce layer: h = h0 = ann @ rW + rb (K-pipelined, 128-node tiles)
    k_gemm_red<<<ntiles, 256, 0, stream>>>(ann, rW, rb, h, h0);

    // ---- pre-loop trans of h0 into buf1
    k_gemm<<<dim3(4, ntiles), 256, 0, stream>>>(h, 64, 64, W256, 256, b256,
                                                buf1, nullptr, 256);

    // ---- message-passing steps: aggregate + fused GRU/trans (trans skipped on last step)
    for (int s = 0; s < NSTEPS; ++s) {
        k_aggregate<<<N_NODES / 4, 256, 0, stream>>>(buf1, rs, colidx, abuf);
        k_gruF3<<<(N_NODES + 63) / 64, 256, 0, stream>>>(abuf, WiA, biA, Wh192, bh192,
                                                         W256, b256, h, buf1,
                                                         (s < NSTEPS - 1) ? 1 : 0);
    }

    // ---- pooling + classifier (atomic-free, multi-block)
    k_gate2<<<N_NODES / 4, 256, 0, stream>>>(h, h0, gW, gb, gate);
    k_poolA<<<dim3(NGRAPH, PS), 64, 0, stream>>>(gate, start, pmax);
    k_poolB<<<1, 64, 0, stream>>>(pmax, gm);
    k_poolC<<<dim3(NGRAPH, PS), 256, 0, stream>>>(h, h0, gate, start, gm, pnum, pden);
    k_poolD<<<NGRAPH, 128, 0, stream>>>(pnum, pden, ro);
    k_logits<<<1, 128, 0, stream>>>(ro, oW, ob, out);
}